// Round 8
// baseline (411.353 us; speedup 1.0000x reference)
//
#include <hip/hip_runtime.h>

typedef unsigned short ushort_t;
typedef unsigned int u32;
typedef unsigned long long u64;
typedef __attribute__((ext_vector_type(8))) short bf16x8;   // 8 bf16 in 4 VGPRs
typedef __attribute__((ext_vector_type(4))) float f32x4;

#define N_ROWS 65536
#define K_EMB  2048
#define D_DIM  512
// d_out float offsets (outputs concatenated in return order)
#define OFF_ZQ   0
#define OFF_IDX  33554432
#define OFF_LOSS 33619968
#define OFF_EMB  33619969
#define OFF_NCS  34668545
#define OFF_NEA  34670593
#define TAU 1.5f
#define CHUNK 128
#define MAXCHUNK 2560

__device__ __forceinline__ ushort_t f2bf(float f) {
  u32 u = __float_as_uint(f);
  u32 r = (u + 0x7fffu + ((u >> 16) & 1u)) >> 16;   // RNE
  return (ushort_t)r;
}
__device__ __forceinline__ void glds16(const void* g, void* l) {
  __builtin_amdgcn_global_load_lds((const __attribute__((address_space(1))) u32*)g,
                                   (__attribute__((address_space(3))) u32*)l, 16, 0, 0);
}

// merge two ascending quads (s,o), keep 4 smallest ascending in s
#define MERGE4(s1,s2,s3,s4,o1,o2,o3,o4) do {                        \
    u32 x1 = min(s1,o4), x2 = min(s2,o3), x3 = min(s3,o2), x4 = min(s4,o1); \
    u32 t1 = min(x1,x3), t3 = max(x1,x3), t2 = min(x2,x4), t4 = max(x2,x4); \
    s1 = min(t1,t2); s2 = max(t1,t2); s3 = min(t3,t4); s4 = max(t3,t4);     \
  } while (0)

// ---- prep: bf16 round of z_e (stored in d_out z_q section as scratch) ----
__global__ void prep_z_kernel(const float* __restrict__ ze, ushort_t* __restrict__ xh,
                              float* __restrict__ counts, float* __restrict__ lossws)
{
  int gid = blockIdx.x * 256 + threadIdx.x;          // grid 8192
  const float4* zin = (const float4*)ze;
  ushort4* xh4 = (ushort4*)xh;
  for (int g = gid; g < (N_ROWS * D_DIM / 4); g += 8192 * 256) {
    float4 v = zin[g];
    ushort4 h;
    h.x = f2bf(v.x); h.y = f2bf(v.y); h.z = f2bf(v.z); h.w = f2bf(v.w);
    xh4[g] = h;
  }
  if (gid < K_EMB) counts[gid] = 0.0f;
  if (gid == 0) lossws[0] = 0.0f;
}

// ---- prep: bf16 round of embedding + fp32 row norms ----
__global__ void prep_e_kernel(const float* __restrict__ emb, ushort_t* __restrict__ eh,
                              float* __restrict__ enorm)
{
  int w = threadIdx.x >> 6, l = threadIdx.x & 63;
  int k = blockIdx.x * 4 + w;                        // grid 512 -> 2048 rows
  const float4* row = (const float4*)(emb + (size_t)k * D_DIM);
  float4 a = row[l * 2], b = row[l * 2 + 1];
  ushort4 h0, h1;
  h0.x = f2bf(a.x); h0.y = f2bf(a.y); h0.z = f2bf(a.z); h0.w = f2bf(a.w);
  h1.x = f2bf(b.x); h1.y = f2bf(b.y); h1.z = f2bf(b.z); h1.w = f2bf(b.w);
  ((ushort4*)(eh + (size_t)k * D_DIM))[l * 2] = h0;
  ((ushort4*)(eh + (size_t)k * D_DIM))[l * 2 + 1] = h1;
  float s = a.x*a.x + a.y*a.y + a.z*a.z + a.w*a.w + b.x*b.x + b.y*b.y + b.z*b.z + b.w*b.w;
  #pragma unroll
  for (int off = 32; off >= 1; off >>= 1) s += __shfl_xor(s, off);
  if (l == 0) enorm[k] = s;
}

// ---- main distance GEMM: 256x256 tile, 8 waves, BK=32, 3-deep LDS ring ----
// grid 2048 = ct*256 + rt (same-rt blocks -> same XCD for A-stripe L2 reuse).
// Per K-tile iteration: STAGE(t+2) into ring[(t+2)%3] (buffer not in use ->
// race-free), ds_read 12 frags from ring[t%3], setprio-wrapped 32 MFMA/wave,
// counted s_waitcnt vmcnt(4) (tile t+1 landed, t+2 stays in flight ACROSS the
// raw s_barrier -- no __syncthreads vmcnt(0) drain).
// LDS rows are 64B (4 granules); swizzle granule g at slot g^(r&3): 64-lane
// b128 frag reads hit 64 distinct slots -> conflict-free.
// Keys: raw fp32 dist bits (positive) top21 | col11. Per-block per-row top-4
// over 256 cols -> list[row][8 tiles] (32 cands/row).
__global__ __launch_bounds__(512, 2)
void dist_gemm(const ushort_t* __restrict__ xh, const ushort_t* __restrict__ eh,
               const float* __restrict__ enorm, u32* __restrict__ list)
{
  __shared__ char Ring[3 * 32768];                   // [ring][A 16KB | B 16KB]
  const int t256 = threadIdx.x;
  const int w = t256 >> 6, l = t256 & 63;
  const int li = l & 15, lg = l >> 4;
  const int bx = blockIdx.x;
  const int rt = bx & 255, ct = bx >> 8;
  const int row0 = rt << 8, col0 = ct << 8;
  const int wm = w >> 2, wn = w & 3;                 // 2M x 4N waves, tile 128x64

  f32x4 acc[8][4];
  #pragma unroll
  for (int m = 0; m < 8; ++m)
    #pragma unroll
    for (int n = 0; n < 4; ++n) acc[m][n] = (f32x4){0.f, 0.f, 0.f, 0.f};

#define STAGE(ring_, t_) do {                                                  \
    const int kb_ = (t_) << 6;                                                 \
    _Pragma("unroll")                                                          \
    for (int i = 0; i < 2; ++i) {                                              \
      int G = (i << 9) + (w << 6) + l;               /* granule 0..1023 */     \
      int r_ = G >> 2, gp_ = G & 3;                                            \
      int cb_ = gp_ ^ (r_ & 3);                      /* pre-swizzled source */ \
      size_t gA = ((size_t)(row0 + r_) << 10) + kb_ + (cb_ << 4);              \
      size_t gB = ((size_t)(col0 + r_) << 10) + kb_ + (cb_ << 4);              \
      int ld_ = ((i << 9) + (w << 6)) << 4;          /* wave-uniform base */   \
      glds16((const char*)xh + gA, Ring + (ring_) * 32768 + ld_);              \
      glds16((const char*)eh + gB, Ring + (ring_) * 32768 + 16384 + ld_);      \
    }                                                                          \
  } while (0)

  // prologue: stage tiles 0 and 1; wait tile 0; barrier
  STAGE(0, 0);
  STAGE(1, 1);
  asm volatile("s_waitcnt vmcnt(4)" ::: "memory");
  __builtin_amdgcn_s_barrier();

  #pragma unroll
  for (int t = 0; t < 16; ++t) {
    const int rg = t % 3;
    if (t + 2 < 16) STAGE((t + 2) % 3, t + 2);       // issue early, fly under MFMA
    const char* base = Ring + rg * 32768;
    bf16x8 fa[8], fb[4];
    #pragma unroll
    for (int m = 0; m < 8; ++m) {
      int r = (wm << 7) + (m << 4) + li;
      fa[m] = *(const bf16x8*)(base + (r << 6) + ((lg ^ (r & 3)) << 4));
    }
    #pragma unroll
    for (int n = 0; n < 4; ++n) {
      int r = (wn << 6) + (n << 4) + li;
      fb[n] = *(const bf16x8*)(base + 16384 + (r << 6) + ((lg ^ (r & 3)) << 4));
    }
    __builtin_amdgcn_s_setprio(1);
    #pragma unroll
    for (int m = 0; m < 8; ++m)
      #pragma unroll
      for (int n = 0; n < 4; ++n)
        acc[m][n] = __builtin_amdgcn_mfma_f32_16x16x32_bf16(fa[m], fb[n], acc[m][n], 0, 0, 0);
    __builtin_amdgcn_s_setprio(0);
    if (t + 2 < 16) {
      asm volatile("s_waitcnt vmcnt(4)" ::: "memory"); // t+1 landed; t+2 in flight
    } else if (t + 1 < 16) {
      asm volatile("s_waitcnt vmcnt(0)" ::: "memory"); // drain tail
    }
    asm volatile("" ::: "memory");
    __builtin_amdgcn_s_barrier();
  }
#undef STAGE

  // epilogue: per-row top-4 over this block's 256 cols
  float en[4];
  const int colb = col0 + (wn << 6) + li;
  #pragma unroll
  for (int n = 0; n < 4; ++n) en[n] = enorm[colb + (n << 4)];

  uint4* ex = (uint4*)Ring;                          // [256 rows][4 wn]
  #pragma unroll
  for (int m = 0; m < 8; ++m) {
    #pragma unroll
    for (int i = 0; i < 4; ++i) {
      // C/D: col = lane&15 (li), row = (lane>>4)*4 + reg
      int lrow = (wm << 7) + (m << 4) + (lg << 2) + i;
      u32 k0 = (__float_as_uint(fmaf(-2.f, acc[m][0][i], en[0])) & 0xFFFFF800u) | (u32)colb;
      u32 k1 = (__float_as_uint(fmaf(-2.f, acc[m][1][i], en[1])) & 0xFFFFF800u) | (u32)(colb + 16);
      u32 k2 = (__float_as_uint(fmaf(-2.f, acc[m][2][i], en[2])) & 0xFFFFF800u) | (u32)(colb + 32);
      u32 k3 = (__float_as_uint(fmaf(-2.f, acc[m][3][i], en[3])) & 0xFFFFF800u) | (u32)(colb + 48);
      // sort4 ascending
      u32 a = min(k0, k1), b = max(k0, k1);
      u32 c = min(k2, k3), d = max(k2, k3);
      u32 e = min(a, c),  f = max(a, c);
      u32 g = min(b, d),  h = max(b, d);
      u32 s1 = e, s2 = min(f, g), s3 = max(f, g), s4 = h;
      // merge across the 16 li lanes (lg preserved under xor<16)
      #pragma unroll
      for (int off = 1; off <= 8; off <<= 1) {
        u32 o1 = __shfl_xor(s1, off), o2 = __shfl_xor(s2, off);
        u32 o3 = __shfl_xor(s3, off), o4 = __shfl_xor(s4, off);
        MERGE4(s1, s2, s3, s4, o1, o2, o3, o4);
      }
      if (li == 0) {
        uint4 v; v.x = s1; v.y = s2; v.z = s3; v.w = s4;
        ex[(lrow << 2) + wn] = v;
      }
    }
  }
  asm volatile("" ::: "memory");
  __builtin_amdgcn_s_barrier();
  if (t256 < 256) {
    uint4 v0 = ex[(t256 << 2) + 0];
    uint4 v1 = ex[(t256 << 2) + 1];
    uint4 v2 = ex[(t256 << 2) + 2];
    uint4 v3 = ex[(t256 << 2) + 3];
    u32 s1 = v0.x, s2 = v0.y, s3 = v0.z, s4 = v0.w;
    MERGE4(s1, s2, s3, s4, v1.x, v1.y, v1.z, v1.w);
    MERGE4(s1, s2, s3, s4, v2.x, v2.y, v2.z, v2.w);
    MERGE4(s1, s2, s3, s4, v3.x, v3.y, v3.z, v3.w);
    uint4 v; v.x = s1; v.y = s2; v.z = s3; v.w = s4;
    *(uint4*)&list[(((size_t)(row0 + t256)) << 5) + (ct << 2)] = v;
  }
}

// ---- finalize argmin: 32 cands/row (lane-held); fp64 rescore on near-ties ----
// also builds the cluster histogram (counts) for the counting sort.
__global__ void finalize_kernel(const u32* __restrict__ list, const float* __restrict__ ze,
                                const float* __restrict__ emb, int* __restrict__ wsidx,
                                float* __restrict__ counts)
{
  int w = threadIdx.x >> 6, l = threadIdx.x & 63;
  int row = blockIdx.x * 4 + w;                      // grid 16384
  u32 ent = (l < 32) ? list[(((size_t)row) << 5) + l] : 0xFFFFFFFFu;
  u32 e1 = ent;
  #pragma unroll
  for (int off = 32; off >= 1; off >>= 1) e1 = min(e1, __shfl_xor(e1, off));
  float d1 = __uint_as_float(e1 & 0xFFFFF800u);
  float dl = __uint_as_float(ent & 0xFFFFF800u);    // l>=32 decodes to NaN -> false
  u64 mask = __ballot(dl < d1 + TAU);
  int idx;
  if (__popcll(mask) <= 1) {
    idx = (int)(e1 & 2047u);
  } else {
    double bd = 1e300; int bc = 0x7fffffff;
    const float* xr = ze + (((size_t)row) << 9);
    double xv[8];
    #pragma unroll
    for (int p = 0; p < 8; ++p) xv[p] = (double)xr[(l << 3) + p];
    u64 mm = mask;
    while (mm) {
      int j = (int)(__ffsll((long long)mm) - 1);
      mm &= mm - 1;
      u32 cj = __shfl(ent, j);
      int col = (int)(cj & 2047u);
      const float* er = emb + (((size_t)col) << 9);
      double s = 0.0;
      #pragma unroll
      for (int p = 0; p < 8; ++p) {
        double df = xv[p] - (double)er[(l << 3) + p];
        s += df * df;
      }
      #pragma unroll
      for (int off = 32; off >= 1; off >>= 1) s += __shfl_xor(s, off);
      if (s < bd || (s == bd && col < bc)) { bd = s; bc = col; }
    }
    idx = bc;
  }
  if (l == 0) {
    wsidx[row] = idx;
    atomicAdd(&counts[idx], 1.0f);
  }
}

// ---- single-block scan: offsets from counts, zero cursors, emit chunk list ----
__global__ void scan_kernel(const float* __restrict__ counts, u32* __restrict__ offsets,
                            u32* __restrict__ cursor, u32* __restrict__ chunkinfo,
                            u32* __restrict__ ntotal)
{
  int t = threadIdx.x;                               // 1 block, 256 threads
  int c[8]; int s = 0;
  #pragma unroll
  for (int i = 0; i < 8; ++i) { c[i] = (int)counts[t * 8 + i]; s += c[i]; }
  __shared__ int ts[256];
  ts[t] = s; __syncthreads();
  for (int off = 1; off < 256; off <<= 1) {
    int v = (t >= off) ? ts[t - off] : 0;
    __syncthreads();
    ts[t] += v;
    __syncthreads();
  }
  int run = ts[t] - s;                               // exclusive prefix
  int nch[8]; int ns = 0;
  #pragma unroll
  for (int i = 0; i < 8; ++i) {
    offsets[t * 8 + i] = (u32)run;
    cursor[t * 8 + i] = 0;
    run += c[i];
    nch[i] = (c[i] + CHUNK - 1) / CHUNK;
    ns += nch[i];
  }
  __shared__ int ts2[256];
  ts2[t] = ns; __syncthreads();
  for (int off = 1; off < 256; off <<= 1) {
    int v = (t >= off) ? ts2[t - off] : 0;
    __syncthreads();
    ts2[t] += v;
    __syncthreads();
  }
  int cb = ts2[t] - ns;
  #pragma unroll
  for (int i = 0; i < 8; ++i)
    for (int cc = 0; cc < nch[i]; ++cc)
      chunkinfo[cb++] = (u32)(t * 8 + i) | ((u32)cc << 11);
  if (t == 255) *ntotal = (u32)ts2[255];
}

// ---- scatter rows into cluster-sorted order ----
__global__ void scatter_kernel(const int* __restrict__ wsidx, const u32* __restrict__ offsets,
                               u32* __restrict__ cursor, u32* __restrict__ sorted)
{
  int row = blockIdx.x * 256 + threadIdx.x;          // grid 256
  int idx = wsidx[row];
  u32 pos = atomicAdd(&cursor[idx], 1u);
  sorted[offsets[idx] + pos] = (u32)row;
}

// ---- zero esum rows only where needed (empty or multi-chunk clusters) ----
__global__ void zesum_kernel(const float* __restrict__ counts, float* __restrict__ esum)
{
  int k = blockIdx.x;                                // grid 2048
  float c = counts[k];
  if (c == 0.0f || c > (float)CHUNK) {
    esum[((size_t)k << 9) + threadIdx.x] = 0.0f;
    esum[((size_t)k << 9) + 256 + threadIdx.x] = 0.0f;
  }
}

// ---- per-chunk fused: z_q write, idx, loss, segment sum (store; atomics only if >CHUNK) ----
__global__ __launch_bounds__(256)
void zq_seg_kernel(const float* __restrict__ ze, const float* __restrict__ emb,
                   const u32* __restrict__ offsets, const float* __restrict__ counts,
                   const u32* __restrict__ sorted, const u32* __restrict__ chunkinfo,
                   const u32* __restrict__ ntotal, float* __restrict__ o_zq,
                   float* __restrict__ o_idx, float* __restrict__ esum,
                   float* __restrict__ lossws)
{
  int cid = blockIdx.x;                              // grid MAXCHUNK
  if (cid >= (int)*ntotal) return;
  u32 rec = chunkinfo[cid];
  int k = rec & 2047, c = (int)(rec >> 11);
  int ctotal = (int)counts[k];
  int base = (int)offsets[k] + c * CHUNK;
  int cnt = min(ctotal - c * CHUNK, CHUNK);
  bool multi = ctotal > CHUNK;
  int t = threadIdx.x, w = t >> 6, l = t & 63;
  __shared__ u32 srow[CHUNK];
  __shared__ float sacc[4 * 512];
  __shared__ float sloss[4];
  if (t < cnt) srow[t] = sorted[base + t];
  __syncthreads();
  const float4* e4 = (const float4*)(emb + ((size_t)k << 9));
  float4 ev0 = e4[l * 2], ev1 = e4[l * 2 + 1];
  float a0x=0,a0y=0,a0z=0,a0w=0,a1x=0,a1y=0,a1z=0,a1w=0;
  float lacc = 0.f;
  for (int r = w; r < cnt; r += 4) {
    int row = (int)srow[r];
    const float4* z4 = (const float4*)(ze + ((size_t)row << 9));
    float4 zv0 = z4[l * 2], zv1 = z4[l * 2 + 1];
    float4 q0, q1;
    q0.x = zv0.x + (ev0.x - zv0.x);
    q0.y = zv0.y + (ev0.y - zv0.y);
    q0.z = zv0.z + (ev0.z - zv0.z);
    q0.w = zv0.w + (ev0.w - zv0.w);
    q1.x = zv1.x + (ev1.x - zv1.x);
    q1.y = zv1.y + (ev1.y - zv1.y);
    q1.z = zv1.z + (ev1.z - zv1.z);
    q1.w = zv1.w + (ev1.w - zv1.w);
    float4* zq4 = (float4*)(o_zq + ((size_t)row << 9));
    zq4[l * 2] = q0; zq4[l * 2 + 1] = q1;
    float dx = zv0.x - q0.x, dy = zv0.y - q0.y, dz = zv0.z - q0.z, dw = zv0.w - q0.w;
    lacc += dx*dx + dy*dy + dz*dz + dw*dw;
    dx = zv1.x - q1.x; dy = zv1.y - q1.y; dz = zv1.z - q1.z; dw = zv1.w - q1.w;
    lacc += dx*dx + dy*dy + dz*dz + dw*dw;
    a0x += zv0.x; a0y += zv0.y; a0z += zv0.z; a0w += zv0.w;
    a1x += zv1.x; a1y += zv1.y; a1z += zv1.z; a1w += zv1.w;
    if (l == 0) o_idx[row] = (float)k;
  }
  #pragma unroll
  for (int off = 32; off >= 1; off >>= 1) lacc += __shfl_xor(lacc, off);
  if (l == 0) sloss[w] = lacc;
  float* sa = sacc + w * 512 + l * 8;
  sa[0]=a0x; sa[1]=a0y; sa[2]=a0z; sa[3]=a0w; sa[4]=a1x; sa[5]=a1y; sa[6]=a1z; sa[7]=a1w;
  __syncthreads();
  #pragma unroll
  for (int j = 0; j < 2; ++j) {
    int col = t * 2 + j;
    float v = sacc[col] + sacc[512 + col] + sacc[1024 + col] + sacc[1536 + col];
    if (multi) atomicAdd(&esum[((size_t)k << 9) + col], v);
    else       esum[((size_t)k << 9) + col] = v;
  }
  if (t == 0) atomicAdd(lossws, sloss[0] + sloss[1] + sloss[2] + sloss[3]);
}

// ---- cluster-size EMA + smoothing factors + loss ----
__global__ void d1_kernel(const float* __restrict__ cs, const float* __restrict__ counts,
                          float* __restrict__ o_ncs, float* __restrict__ inv,
                          const float* __restrict__ lossws, float* __restrict__ o_loss)
{
  int t = threadIdx.x;                               // single block, 256 threads
  float ncs[8]; float s = 0.0f;
  #pragma unroll
  for (int i = 0; i < 8; ++i) {
    int k = t + (i << 8);
    float v = 0.99f * cs[k] + 0.01f * counts[k];
    ncs[i] = v; o_ncs[k] = v; s += v;
  }
  __shared__ float red[256];
  red[t] = s; __syncthreads();
  for (int h = 128; h >= 1; h >>= 1) { if (t < h) red[t] += red[t + h]; __syncthreads(); }
  float n = red[0];
  float denom = n + 2048.0f * 1e-5f;
  #pragma unroll
  for (int i = 0; i < 8; ++i) {
    int k = t + (i << 8);
    float sm = (ncs[i] + 1e-5f) / denom * n;
    inv[k] = 1.0f / sm;
  }
  if (t == 0) o_loss[0] = lossws[0] * 1.25f / 33554432.0f;
}

// ---- embed_avg EMA + new embedding ----
__global__ void d2_kernel(const float* __restrict__ ea, const float* __restrict__ inv,
                          float* __restrict__ o_emb, float* __restrict__ o_nea)
{
  int gid = blockIdx.x * 256 + threadIdx.x;          // grid 1024
  for (int i = gid; i < K_EMB * D_DIM; i += 1024 * 256) {
    float es = o_emb[i];                             // segment sum (scratch)
    float nea = 0.99f * ea[i] + 0.01f * es;
    o_nea[i] = nea;
    o_emb[i] = nea * inv[i >> 9];
  }
}

extern "C" void kernel_launch(void* const* d_in, const int* in_sizes, int n_in,
                              void* d_out, int out_size, void* d_ws, size_t ws_size,
                              hipStream_t stream)
{
  const float* ze  = (const float*)d_in[0];
  const float* emb = (const float*)d_in[1];
  const float* cs  = (const float*)d_in[2];
  const float* ea  = (const float*)d_in[3];
  float* out = (float*)d_out;
  float* o_zq   = out + OFF_ZQ;
  float* o_idx  = out + OFF_IDX;
  float* o_loss = out + OFF_LOSS;
  float* o_emb  = out + OFF_EMB;
  float* o_ncs  = out + OFF_NCS;
  float* o_nea  = out + OFF_NEA;
  // d_out self-scratch (inside the 134 MB z_q section, consumed by finalize
  // before zq_seg overwrites it): xh = bf16 z_e at bytes [0,64MB),
  // candidate list at bytes [64MB,72MB) = [65536][32] u32.
  ushort_t* xh = (ushort_t*)d_out;
  u32* list    = (u32*)(out + 16777216);
  // workspace layout
  char* ws = (char*)d_ws;
  ushort_t* ehp = (ushort_t*)ws;                     // 2 MB
  int* wsidx    = (int*)(ws + 2097152);              // 256 KB
  float* counts = (float*)(ws + 2097152 + 262144);   // 8 KB
  float* enorm  = counts + 2048;                     // 8 KB
  float* inv    = enorm + 2048;                      // 8 KB
  float* lossws = inv + 2048;                        // 4 B (+pad)
  u32* offsets  = (u32*)(lossws + 64);               // 8 KB
  u32* cursor   = offsets + 2048;                    // 8 KB
  u32* sorted   = cursor + 2048;                     // 256 KB
  u32* chunkinfo= sorted + 65536;                    // 10 KB
  u32* ntotal   = chunkinfo + MAXCHUNK;              // 4 B

  prep_z_kernel<<<8192, 256, 0, stream>>>(ze, xh, counts, lossws);
  prep_e_kernel<<<512, 256, 0, stream>>>(emb, ehp, enorm);
  dist_gemm<<<2048, 512, 0, stream>>>(xh, ehp, enorm, list);
  finalize_kernel<<<16384, 256, 0, stream>>>(list, ze, emb, wsidx, counts);
  scan_kernel<<<1, 256, 0, stream>>>(counts, offsets, cursor, chunkinfo, ntotal);
  scatter_kernel<<<256, 256, 0, stream>>>(wsidx, offsets, cursor, sorted);
  zesum_kernel<<<2048, 256, 0, stream>>>(counts, o_emb);
  zq_seg_kernel<<<MAXCHUNK, 256, 0, stream>>>(ze, emb, offsets, counts, sorted,
                                              chunkinfo, ntotal, o_zq, o_idx, o_emb, lossws);
  d1_kernel<<<1, 256, 0, stream>>>(cs, counts, o_ncs, inv, lossws, o_loss);
  d2_kernel<<<1024, 256, 0, stream>>>(ea, inv, o_emb, o_nea);
}

// Round 9
// 343.679 us; speedup vs baseline: 1.1969x; 1.1969x over previous
//
#include <hip/hip_runtime.h>

typedef unsigned short ushort_t;
typedef unsigned int u32;
typedef unsigned long long u64;
typedef __attribute__((ext_vector_type(8))) short bf16x8;   // 8 bf16 in 4 VGPRs
typedef __attribute__((ext_vector_type(4))) float f32x4;

#define N_ROWS 65536
#define K_EMB  2048
#define D_DIM  512
// d_out float offsets (outputs concatenated in return order)
#define OFF_ZQ   0
#define OFF_IDX  33554432
#define OFF_LOSS 33619968
#define OFF_EMB  33619969
#define OFF_NCS  34668545
#define OFF_NEA  34670593
#define TAU 1.5f
#define CHUNK 128
#define MAXCHUNK 2560

__device__ __forceinline__ ushort_t f2bf(float f) {
  u32 u = __float_as_uint(f);
  u32 r = (u + 0x7fffu + ((u >> 16) & 1u)) >> 16;   // RNE
  return (ushort_t)r;
}
__device__ __forceinline__ void glds16(const void* g, void* l) {
  __builtin_amdgcn_global_load_lds((const __attribute__((address_space(1))) u32*)g,
                                   (__attribute__((address_space(3))) u32*)l, 16, 0, 0);
}

// merge two ascending quads (s,o), keep 4 smallest ascending in s
#define MERGE4(s1,s2,s3,s4,o1,o2,o3,o4) do {                        \
    u32 x1 = min(s1,o4), x2 = min(s2,o3), x3 = min(s3,o2), x4 = min(s4,o1); \
    u32 t1 = min(x1,x3), t3 = max(x1,x3), t2 = min(x2,x4), t4 = max(x2,x4); \
    s1 = min(t1,t2); s2 = max(t1,t2); s3 = min(t3,t4); s4 = max(t3,t4);     \
  } while (0)

// ---- merged prep: blocks 0..511 = embedding split + norms; 512.. = z_e split ----
__global__ void prep_kernel(const float* __restrict__ ze, const float* __restrict__ emb,
                            ushort_t* __restrict__ xh, ushort_t* __restrict__ eh,
                            float* __restrict__ enorm, float* __restrict__ counts,
                            float* __restrict__ lossws)
{
  int bx = blockIdx.x;
  int t = threadIdx.x;
  if (bx < 512) {
    int w = t >> 6, l = t & 63;
    int k = bx * 4 + w;                              // 2048 rows
    const float4* row = (const float4*)(emb + (size_t)k * D_DIM);
    float4 a = row[l * 2], b = row[l * 2 + 1];
    ushort4 h0, h1;
    h0.x = f2bf(a.x); h0.y = f2bf(a.y); h0.z = f2bf(a.z); h0.w = f2bf(a.w);
    h1.x = f2bf(b.x); h1.y = f2bf(b.y); h1.z = f2bf(b.z); h1.w = f2bf(b.w);
    ((ushort4*)(eh + (size_t)k * D_DIM))[l * 2] = h0;
    ((ushort4*)(eh + (size_t)k * D_DIM))[l * 2 + 1] = h1;
    float s = a.x*a.x + a.y*a.y + a.z*a.z + a.w*a.w + b.x*b.x + b.y*b.y + b.z*b.z + b.w*b.w;
    #pragma unroll
    for (int off = 32; off >= 1; off >>= 1) s += __shfl_xor(s, off);
    if (l == 0) enorm[k] = s;
  } else {
    int gid = (bx - 512) * 256 + t;                  // 8192-block portion
    const float4* zin = (const float4*)ze;
    ushort4* xh4 = (ushort4*)xh;
    for (int g = gid; g < (N_ROWS * D_DIM / 4); g += 8192 * 256) {
      float4 v = zin[g];
      ushort4 h;
      h.x = f2bf(v.x); h.y = f2bf(v.y); h.z = f2bf(v.z); h.w = f2bf(v.w);
      xh4[g] = h;
    }
    if (gid < K_EMB) counts[gid] = 0.0f;
    if (gid == 0) lossws[0] = 0.0f;
  }
}

// ---- main distance GEMM: round-4 structure + T3-minimum 2-phase dbuf ----
// grid 512: each block = 128 rows x all 2048 cols, 16 col-tiles, BK=64.
// 4 waves (2x2), wave tile 64x64, 16x16x32 MFMA, proven ^(r&7) 128B-row LDS
// swizzle (conflict-free), global_load_lds. Double-buffered 2x32KB: STAGE(s+1)
// issued BEFORE compute(s), ONE __syncthreads per step (drains vmcnt after the
// loads had the whole compute phase to fly). launch_bounds(256,2): no spill.
// Keys: raw fp32 dist bits (positive) top21 | col11. Per-lane running top-4,
// one cross-lane merge at block end -> global per-row top-4.
__global__ __launch_bounds__(256, 2)
void dist_gemm(const ushort_t* __restrict__ xh, const ushort_t* __restrict__ eh,
               const float* __restrict__ enorm, uint4* __restrict__ list)
{
  __shared__ ushort_t Ah[2][128 * 64];
  __shared__ ushort_t Bh[2][128 * 64];
  const int t = threadIdx.x;
  const int w = t >> 6, l = t & 63;
  const int li = l & 15, lg = l >> 4;
  const int row0 = blockIdx.x << 7;
  const int wr = (w >> 1) << 6, wc = (w & 1) << 6;

  u32 cand[16][4];
  #pragma unroll
  for (int mi = 0; mi < 16; ++mi) {
    cand[mi][0] = 0xFFFFFFFFu; cand[mi][1] = 0xFFFFFFFFu;
    cand[mi][2] = 0xFFFFFFFFu; cand[mi][3] = 0xFFFFFFFFu;
  }

  f32x4 acc[4][4];
  #pragma unroll
  for (int m = 0; m < 4; ++m)
    #pragma unroll
    for (int n = 0; n < 4; ++n) acc[m][n] = (f32x4){0.f, 0.f, 0.f, 0.f};

  const int Gbase = (w << 6) + l;

  // stage step s = ct*8 + kit into buffer buf_
#define STAGE(buf_, s_) do {                                                   \
    int kb_ = ((s_) & 7) << 7;                                                 \
    int c0_ = ((s_) >> 3) << 7;                                                \
    _Pragma("unroll")                                                          \
    for (int i = 0; i < 4; ++i) {                                              \
      int G = (i << 8) + Gbase;                      /* granule 0..1023 */     \
      int r = G >> 3, gp = G & 7;                                              \
      int cb = gp ^ (r & 7);                         /* pre-swizzled source */ \
      size_t gA = ((size_t)(row0 + r) << 10) + kb_ + (cb << 4);                \
      size_t gB = ((size_t)(c0_ + r) << 10) + kb_ + (cb << 4);                 \
      int ld = ((i << 8) + (w << 6)) << 4;           /* wave-uniform base */   \
      glds16((const char*)xh + gA, (char*)Ah[buf_] + ld);                      \
      glds16((const char*)eh + gB, (char*)Bh[buf_] + ld);                      \
    }                                                                          \
  } while (0)

  STAGE(0, 0);
  __syncthreads();
  int buf = 0;
  float en0 = 0.f, en1 = 0.f, en2 = 0.f, en3 = 0.f;

  for (int s = 0; s < 128; ++s) {
    if ((s & 7) == 0) {                              // prefetch this tile's norms
      int col0 = (s >> 3) << 7;
      en0 = enorm[col0 + wc + 0  + li];
      en1 = enorm[col0 + wc + 16 + li];
      en2 = enorm[col0 + wc + 32 + li];
      en3 = enorm[col0 + wc + 48 + li];
    }
    if (s != 127) STAGE(buf ^ 1, s + 1);             // loads fly under compute

    #pragma unroll
    for (int kblk = 0; kblk < 2; ++kblk) {
      bf16x8 fah[4], fbh[4];
      #pragma unroll
      for (int m = 0; m < 4; ++m) {
        int r = wr + (m << 4) + li;
        int c = (kblk << 2) + lg;
        int off = (r << 7) + ((c ^ (r & 7)) << 4);   // swizzled read
        fah[m] = *(const bf16x8*)((const char*)Ah[buf] + off);
      }
      #pragma unroll
      for (int n = 0; n < 4; ++n) {
        int r = wc + (n << 4) + li;
        int c = (kblk << 2) + lg;
        int off = (r << 7) + ((c ^ (r & 7)) << 4);
        fbh[n] = *(const bf16x8*)((const char*)Bh[buf] + off);
      }
      #pragma unroll
      for (int m = 0; m < 4; ++m)
        #pragma unroll
        for (int n = 0; n < 4; ++n)
          acc[m][n] = __builtin_amdgcn_mfma_f32_16x16x32_bf16(fah[m], fbh[n], acc[m][n], 0, 0, 0);
    }

    if ((s & 7) == 7) {                              // fold this col-tile
      int col0 = (s >> 3) << 7;
      const u32 colb = (u32)(col0 + wc + li);
      #pragma unroll
      for (int m = 0; m < 4; ++m)
        #pragma unroll
        for (int i = 0; i < 4; ++i) {
          u32 k0 = (__float_as_uint(fmaf(-2.f, acc[m][0][i], en0)) & 0xFFFFF800u) | colb;
          u32 k1 = (__float_as_uint(fmaf(-2.f, acc[m][1][i], en1)) & 0xFFFFF800u) | (colb + 16u);
          u32 k2 = (__float_as_uint(fmaf(-2.f, acc[m][2][i], en2)) & 0xFFFFF800u) | (colb + 32u);
          u32 k3 = (__float_as_uint(fmaf(-2.f, acc[m][3][i], en3)) & 0xFFFFF800u) | (colb + 48u);
          // sort4 ascending
          u32 a = min(k0, k1), b = max(k0, k1);
          u32 c = min(k2, k3), d = max(k2, k3);
          u32 e = min(a, c),  f = max(a, c);
          u32 g = min(b, d),  h = max(b, d);
          u32 q1 = e, q2 = min(f, g), q3 = max(f, g), q4 = h;
          MERGE4(cand[m * 4 + i][0], cand[m * 4 + i][1],
                 cand[m * 4 + i][2], cand[m * 4 + i][3], q1, q2, q3, q4);
          acc[m][0][i] = 0.f; acc[m][1][i] = 0.f;
          acc[m][2][i] = 0.f; acc[m][3][i] = 0.f;
        }
    }
    __syncthreads();                                 // drains staged loads too
    buf ^= 1;
  }
#undef STAGE

  // cross-li merge (16 lanes per row-group; lg preserved under xor<16)
  #pragma unroll
  for (int mi = 0; mi < 16; ++mi) {
    u32 s1 = cand[mi][0], s2 = cand[mi][1], s3 = cand[mi][2], s4 = cand[mi][3];
    #pragma unroll
    for (int off = 1; off <= 8; off <<= 1) {
      u32 o1 = __shfl_xor(s1, off), o2 = __shfl_xor(s2, off);
      u32 o3 = __shfl_xor(s3, off), o4 = __shfl_xor(s4, off);
      MERGE4(s1, s2, s3, s4, o1, o2, o3, o4);
    }
    cand[mi][0] = s1; cand[mi][1] = s2; cand[mi][2] = s3; cand[mi][3] = s4;
  }

  // cross wave-pair merge (w0<-w1, w2<-w3) via LDS, then store row top-4
  u32* ex = (u32*)Ah;                                // [128 rows][4 u32]
  if ((w & 1) == 1 && li == 0) {
    #pragma unroll
    for (int m = 0; m < 4; ++m)
      #pragma unroll
      for (int i = 0; i < 4; ++i) {
        int lrow = wr + (m << 4) + (lg << 2) + i;    // C/D: row=(lane>>4)*4+reg
        uint4 v;
        v.x = cand[m * 4 + i][0]; v.y = cand[m * 4 + i][1];
        v.z = cand[m * 4 + i][2]; v.w = cand[m * 4 + i][3];
        *(uint4*)&ex[lrow << 2] = v;
      }
  }
  __syncthreads();
  if ((w & 1) == 0 && li == 0) {
    #pragma unroll
    for (int m = 0; m < 4; ++m)
      #pragma unroll
      for (int i = 0; i < 4; ++i) {
        int lrow = wr + (m << 4) + (lg << 2) + i;
        const u32* p = &ex[lrow << 2];
        u32 s1 = cand[m * 4 + i][0], s2 = cand[m * 4 + i][1];
        u32 s3 = cand[m * 4 + i][2], s4 = cand[m * 4 + i][3];
        u32 o1 = p[0], o2 = p[1], o3 = p[2], o4 = p[3];
        MERGE4(s1, s2, s3, s4, o1, o2, o3, o4);
        uint4 v; v.x = s1; v.y = s2; v.z = s3; v.w = s4;
        list[row0 + lrow] = v;
      }
  }
}

// ---- finalize argmin: 4 cands/row; fp64 rescore on near-ties ----
// also builds the cluster histogram (counts) for the counting sort.
__global__ void finalize_kernel(const uint4* __restrict__ list, const float* __restrict__ ze,
                                const float* __restrict__ emb, int* __restrict__ wsidx,
                                float* __restrict__ counts)
{
  int w = threadIdx.x >> 6, l = threadIdx.x & 63;
  int row = blockIdx.x * 4 + w;                      // grid 16384
  uint4 q = list[row];
  float d1 = __uint_as_float(q.x & 0xFFFFF800u);
  float lim = d1 + TAU;
  bool n2 = (q.y != 0xFFFFFFFFu) && (__uint_as_float(q.y & 0xFFFFF800u) < lim);
  bool n3 = (q.z != 0xFFFFFFFFu) && (__uint_as_float(q.z & 0xFFFFF800u) < lim);
  bool n4 = (q.w != 0xFFFFFFFFu) && (__uint_as_float(q.w & 0xFFFFF800u) < lim);
  int idx;
  if (!(n2 | n3 | n4)) {
    idx = (int)(q.x & 2047u);
  } else {
    double bd = 1e300; int bc = 0x7fffffff;
    const float* xr = ze + (((size_t)row) << 9);
    double xv[8];
    #pragma unroll
    for (int p = 0; p < 8; ++p) xv[p] = (double)xr[(l << 3) + p];
    #pragma unroll
    for (int j = 0; j < 4; ++j) {
      u32 kj = (j == 0) ? q.x : (j == 1) ? q.y : (j == 2) ? q.z : q.w;
      bool ok = (j == 0) || ((kj != 0xFFFFFFFFu) &&
                             (__uint_as_float(kj & 0xFFFFF800u) < lim));
      if (!ok) continue;
      int col = (int)(kj & 2047u);
      const float* er = emb + (((size_t)col) << 9);
      double s = 0.0;
      #pragma unroll
      for (int p = 0; p < 8; ++p) {
        double df = xv[p] - (double)er[(l << 3) + p];
        s += df * df;
      }
      #pragma unroll
      for (int off = 32; off >= 1; off >>= 1) s += __shfl_xor(s, off);
      if (s < bd || (s == bd && col < bc)) { bd = s; bc = col; }
    }
    idx = bc;
  }
  if (l == 0) {
    wsidx[row] = idx;
    atomicAdd(&counts[idx], 1.0f);
  }
}

// ---- single-block scan: offsets from counts, zero cursors, emit chunk list ----
__global__ void scan_kernel(const float* __restrict__ counts, u32* __restrict__ offsets,
                            u32* __restrict__ cursor, u32* __restrict__ chunkinfo,
                            u32* __restrict__ ntotal)
{
  int t = threadIdx.x;                               // 1 block, 256 threads
  int c[8]; int s = 0;
  #pragma unroll
  for (int i = 0; i < 8; ++i) { c[i] = (int)counts[t * 8 + i]; s += c[i]; }
  __shared__ int ts[256];
  ts[t] = s; __syncthreads();
  for (int off = 1; off < 256; off <<= 1) {
    int v = (t >= off) ? ts[t - off] : 0;
    __syncthreads();
    ts[t] += v;
    __syncthreads();
  }
  int run = ts[t] - s;                               // exclusive prefix
  int nch[8]; int ns = 0;
  #pragma unroll
  for (int i = 0; i < 8; ++i) {
    offsets[t * 8 + i] = (u32)run;
    cursor[t * 8 + i] = 0;
    run += c[i];
    nch[i] = (c[i] + CHUNK - 1) / CHUNK;
    ns += nch[i];
  }
  __shared__ int ts2[256];
  ts2[t] = ns; __syncthreads();
  for (int off = 1; off < 256; off <<= 1) {
    int v = (t >= off) ? ts2[t - off] : 0;
    __syncthreads();
    ts2[t] += v;
    __syncthreads();
  }
  int cb = ts2[t] - ns;
  #pragma unroll
  for (int i = 0; i < 8; ++i)
    for (int cc = 0; cc < nch[i]; ++cc)
      chunkinfo[cb++] = (u32)(t * 8 + i) | ((u32)cc << 11);
  if (t == 255) *ntotal = (u32)ts2[255];
}

// ---- scatter rows into cluster-sorted order ----
__global__ void scatter_kernel(const int* __restrict__ wsidx, const u32* __restrict__ offsets,
                               u32* __restrict__ cursor, u32* __restrict__ sorted)
{
  int row = blockIdx.x * 256 + threadIdx.x;          // grid 256
  int idx = wsidx[row];
  u32 pos = atomicAdd(&cursor[idx], 1u);
  sorted[offsets[idx] + pos] = (u32)row;
}

// ---- zero esum rows only where needed (empty or multi-chunk clusters) ----
__global__ void zesum_kernel(const float* __restrict__ counts, float* __restrict__ esum)
{
  int k = blockIdx.x;                                // grid 2048
  float c = counts[k];
  if (c == 0.0f || c > (float)CHUNK) {
    esum[((size_t)k << 9) + threadIdx.x] = 0.0f;
    esum[((size_t)k << 9) + 256 + threadIdx.x] = 0.0f;
  }
}

// ---- per-chunk fused: z_q write, idx, loss, segment sum (store; atomics only if >CHUNK) ----
__global__ __launch_bounds__(256)
void zq_seg_kernel(const float* __restrict__ ze, const float* __restrict__ emb,
                   const u32* __restrict__ offsets, const float* __restrict__ counts,
                   const u32* __restrict__ sorted, const u32* __restrict__ chunkinfo,
                   const u32* __restrict__ ntotal, float* __restrict__ o_zq,
                   float* __restrict__ o_idx, float* __restrict__ esum,
                   float* __restrict__ lossws)
{
  int cid = blockIdx.x;                              // grid MAXCHUNK
  if (cid >= (int)*ntotal) return;
  u32 rec = chunkinfo[cid];
  int k = rec & 2047, c = (int)(rec >> 11);
  int ctotal = (int)counts[k];
  int base = (int)offsets[k] + c * CHUNK;
  int cnt = min(ctotal - c * CHUNK, CHUNK);
  bool multi = ctotal > CHUNK;
  int t = threadIdx.x, w = t >> 6, l = t & 63;
  __shared__ u32 srow[CHUNK];
  __shared__ float sacc[4 * 512];
  __shared__ float sloss[4];
  if (t < cnt) srow[t] = sorted[base + t];
  __syncthreads();
  const float4* e4 = (const float4*)(emb + ((size_t)k << 9));
  float4 ev0 = e4[l * 2], ev1 = e4[l * 2 + 1];
  float a0x=0,a0y=0,a0z=0,a0w=0,a1x=0,a1y=0,a1z=0,a1w=0;
  float lacc = 0.f;
  for (int r = w; r < cnt; r += 4) {
    int row = (int)srow[r];
    const float4* z4 = (const float4*)(ze + ((size_t)row << 9));
    float4 zv0 = z4[l * 2], zv1 = z4[l * 2 + 1];
    float4 q0, q1;
    q0.x = zv0.x + (ev0.x - zv0.x);
    q0.y = zv0.y + (ev0.y - zv0.y);
    q0.z = zv0.z + (ev0.z - zv0.z);
    q0.w = zv0.w + (ev0.w - zv0.w);
    q1.x = zv1.x + (ev1.x - zv1.x);
    q1.y = zv1.y + (ev1.y - zv1.y);
    q1.z = zv1.z + (ev1.z - zv1.z);
    q1.w = zv1.w + (ev1.w - zv1.w);
    float4* zq4 = (float4*)(o_zq + ((size_t)row << 9));
    zq4[l * 2] = q0; zq4[l * 2 + 1] = q1;
    float dx = zv0.x - q0.x, dy = zv0.y - q0.y, dz = zv0.z - q0.z, dw = zv0.w - q0.w;
    lacc += dx*dx + dy*dy + dz*dz + dw*dw;
    dx = zv1.x - q1.x; dy = zv1.y - q1.y; dz = zv1.z - q1.z; dw = zv1.w - q1.w;
    lacc += dx*dx + dy*dy + dz*dz + dw*dw;
    a0x += zv0.x; a0y += zv0.y; a0z += zv0.z; a0w += zv0.w;
    a1x += zv1.x; a1y += zv1.y; a1z += zv1.z; a1w += zv1.w;
    if (l == 0) o_idx[row] = (float)k;
  }
  #pragma unroll
  for (int off = 32; off >= 1; off >>= 1) lacc += __shfl_xor(lacc, off);
  if (l == 0) sloss[w] = lacc;
  float* sa = sacc + w * 512 + l * 8;
  sa[0]=a0x; sa[1]=a0y; sa[2]=a0z; sa[3]=a0w; sa[4]=a1x; sa[5]=a1y; sa[6]=a1z; sa[7]=a1w;
  __syncthreads();
  #pragma unroll
  for (int j = 0; j < 2; ++j) {
    int col = t * 2 + j;
    float v = sacc[col] + sacc[512 + col] + sacc[1024 + col] + sacc[1536 + col];
    if (multi) atomicAdd(&esum[((size_t)k << 9) + col], v);
    else       esum[((size_t)k << 9) + col] = v;
  }
  if (t == 0) atomicAdd(lossws, sloss[0] + sloss[1] + sloss[2] + sloss[3]);
}

// ---- cluster-size EMA + smoothing factors + loss ----
__global__ void d1_kernel(const float* __restrict__ cs, const float* __restrict__ counts,
                          float* __restrict__ o_ncs, float* __restrict__ inv,
                          const float* __restrict__ lossws, float* __restrict__ o_loss)
{
  int t = threadIdx.x;                               // single block, 256 threads
  float ncs[8]; float s = 0.0f;
  #pragma unroll
  for (int i = 0; i < 8; ++i) {
    int k = t + (i << 8);
    float v = 0.99f * cs[k] + 0.01f * counts[k];
    ncs[i] = v; o_ncs[k] = v; s += v;
  }
  __shared__ float red[256];
  red[t] = s; __syncthreads();
  for (int h = 128; h >= 1; h >>= 1) { if (t < h) red[t] += red[t + h]; __syncthreads(); }
  float n = red[0];
  float denom = n + 2048.0f * 1e-5f;
  #pragma unroll
  for (int i = 0; i < 8; ++i) {
    int k = t + (i << 8);
    float sm = (ncs[i] + 1e-5f) / denom * n;
    inv[k] = 1.0f / sm;
  }
  if (t == 0) o_loss[0] = lossws[0] * 1.25f / 33554432.0f;
}

// ---- embed_avg EMA + new embedding ----
__global__ void d2_kernel(const float* __restrict__ ea, const float* __restrict__ inv,
                          float* __restrict__ o_emb, float* __restrict__ o_nea)
{
  int gid = blockIdx.x * 256 + threadIdx.x;          // grid 1024
  for (int i = gid; i < K_EMB * D_DIM; i += 1024 * 256) {
    float es = o_emb[i];                             // segment sum (scratch)
    float nea = 0.99f * ea[i] + 0.01f * es;
    o_nea[i] = nea;
    o_emb[i] = nea * inv[i >> 9];
  }
}

extern "C" void kernel_launch(void* const* d_in, const int* in_sizes, int n_in,
                              void* d_out, int out_size, void* d_ws, size_t ws_size,
                              hipStream_t stream)
{
  const float* ze  = (const float*)d_in[0];
  const float* emb = (const float*)d_in[1];
  const float* cs  = (const float*)d_in[2];
  const float* ea  = (const float*)d_in[3];
  float* out = (float*)d_out;
  float* o_zq   = out + OFF_ZQ;
  float* o_idx  = out + OFF_IDX;
  float* o_loss = out + OFF_LOSS;
  float* o_emb  = out + OFF_EMB;
  float* o_ncs  = out + OFF_NCS;
  float* o_nea  = out + OFF_NEA;
  // d_out self-scratch: bf16 z_e lives in the z_q section (64 MB, consumed
  // by dist_gemm before zq_seg overwrites it).
  ushort_t* xh = (ushort_t*)d_out;
  // workspace layout
  char* ws = (char*)d_ws;
  ushort_t* ehp = (ushort_t*)ws;                     // 2 MB
  int* wsidx    = (int*)(ws + 2097152);              // 256 KB
  float* counts = (float*)(ws + 2097152 + 262144);   // 8 KB
  float* enorm  = counts + 2048;                     // 8 KB
  float* inv    = enorm + 2048;                      // 8 KB
  float* lossws = inv + 2048;                        // 4 B (+pad)
  u32* offsets  = (u32*)(lossws + 64);               // 8 KB
  u32* cursor   = offsets + 2048;                    // 8 KB
  u32* sorted   = cursor + 2048;                     // 256 KB
  u32* chunkinfo= sorted + 65536;                    // 10 KB
  u32* ntotal   = chunkinfo + MAXCHUNK;              // 4 B
  uint4* list   = (uint4*)(ws + 3145728);            // 1 MB, [65536] uint4

  prep_kernel<<<8704, 256, 0, stream>>>(ze, emb, xh, ehp, enorm, counts, lossws);
  dist_gemm<<<512, 256, 0, stream>>>(xh, ehp, enorm, list);
  finalize_kernel<<<16384, 256, 0, stream>>>(list, ze, emb, wsidx, counts);
  scan_kernel<<<1, 256, 0, stream>>>(counts, offsets, cursor, chunkinfo, ntotal);
  scatter_kernel<<<256, 256, 0, stream>>>(wsidx, offsets, cursor, sorted);
  zesum_kernel<<<2048, 256, 0, stream>>>(counts, o_emb);
  zq_seg_kernel<<<MAXCHUNK, 256, 0, stream>>>(ze, emb, offsets, counts, sorted,
                                              chunkinfo, ntotal, o_zq, o_idx, o_emb, lossws);
  d1_kernel<<<1, 256, 0, stream>>>(cs, counts, o_ncs, inv, lossws, o_loss);
  d2_kernel<<<1024, 256, 0, stream>>>(ea, inv, o_emb, o_nea);
}

// Round 10
// 335.417 us; speedup vs baseline: 1.2264x; 1.0246x over previous
//
#include <hip/hip_runtime.h>

typedef unsigned short ushort_t;
typedef unsigned int u32;
typedef unsigned long long u64;
typedef __attribute__((ext_vector_type(8))) short bf16x8;   // 8 bf16 in 4 VGPRs
typedef __attribute__((ext_vector_type(4))) float f32x4;

#define N_ROWS 65536
#define K_EMB  2048
#define D_DIM  512
// d_out float offsets (outputs concatenated in return order)
#define OFF_ZQ   0
#define OFF_IDX  33554432
#define OFF_LOSS 33619968
#define OFF_EMB  33619969
#define OFF_NCS  34668545
#define OFF_NEA  34670593
#define TAU 1.5f
#define CHUNK 128
#define MAXCHUNK 2560

__device__ __forceinline__ ushort_t f2bf(float f) {
  u32 u = __float_as_uint(f);
  u32 r = (u + 0x7fffu + ((u >> 16) & 1u)) >> 16;   // RNE
  return (ushort_t)r;
}
__device__ __forceinline__ void glds16(const void* g, void* l) {
  __builtin_amdgcn_global_load_lds((const __attribute__((address_space(1))) u32*)g,
                                   (__attribute__((address_space(3))) u32*)l, 16, 0, 0);
}

// merge two ascending quads (s,o), keep 4 smallest ascending in s
#define MERGE4(s1,s2,s3,s4,o1,o2,o3,o4) do {                        \
    u32 x1 = min(s1,o4), x2 = min(s2,o3), x3 = min(s3,o2), x4 = min(s4,o1); \
    u32 t1 = min(x1,x3), t3 = max(x1,x3), t2 = min(x2,x4), t4 = max(x2,x4); \
    s1 = min(t1,t2); s2 = max(t1,t2); s3 = min(t3,t4); s4 = max(t3,t4);     \
  } while (0)

// ---- merged prep: blocks 0..511 = embedding split + norms; 512.. = z_e split ----
__global__ void prep_kernel(const float* __restrict__ ze, const float* __restrict__ emb,
                            ushort_t* __restrict__ xh, ushort_t* __restrict__ eh,
                            float* __restrict__ enorm, float* __restrict__ counts,
                            float* __restrict__ lossws)
{
  int bx = blockIdx.x;
  int t = threadIdx.x;
  if (bx < 512) {
    int w = t >> 6, l = t & 63;
    int k = bx * 4 + w;                              // 2048 rows
    const float4* row = (const float4*)(emb + (size_t)k * D_DIM);
    float4 a = row[l * 2], b = row[l * 2 + 1];
    ushort4 h0, h1;
    h0.x = f2bf(a.x); h0.y = f2bf(a.y); h0.z = f2bf(a.z); h0.w = f2bf(a.w);
    h1.x = f2bf(b.x); h1.y = f2bf(b.y); h1.z = f2bf(b.z); h1.w = f2bf(b.w);
    ((ushort4*)(eh + (size_t)k * D_DIM))[l * 2] = h0;
    ((ushort4*)(eh + (size_t)k * D_DIM))[l * 2 + 1] = h1;
    float s = a.x*a.x + a.y*a.y + a.z*a.z + a.w*a.w + b.x*b.x + b.y*b.y + b.z*b.z + b.w*b.w;
    #pragma unroll
    for (int off = 32; off >= 1; off >>= 1) s += __shfl_xor(s, off);
    if (l == 0) enorm[k] = s;
  } else {
    int gid = (bx - 512) * 256 + t;                  // 8192-block portion
    const float4* zin = (const float4*)ze;
    ushort4* xh4 = (ushort4*)xh;
    for (int g = gid; g < (N_ROWS * D_DIM / 4); g += 8192 * 256) {
      float4 v = zin[g];
      ushort4 h;
      h.x = f2bf(v.x); h.y = f2bf(v.y); h.z = f2bf(v.z); h.w = f2bf(v.w);
      xh4[g] = h;
    }
    if (gid < K_EMB) counts[gid] = 0.0f;
    if (gid == 0) lossws[0] = 0.0f;
  }
}

// ---- main distance GEMM (UNCHANGED from round 9: 177us, MfmaUtil 35%) ----
// grid 512: each block = 128 rows x all 2048 cols, 16 col-tiles, BK=64.
// 4 waves (2x2), wave tile 64x64, 16x16x32 MFMA, proven ^(r&7) 128B-row LDS
// swizzle (conflict-free), global_load_lds. Double-buffered 2x32KB: STAGE(s+1)
// issued BEFORE compute(s), ONE __syncthreads per step. launch_bounds(256,2).
__global__ __launch_bounds__(256, 2)
void dist_gemm(const ushort_t* __restrict__ xh, const ushort_t* __restrict__ eh,
               const float* __restrict__ enorm, uint4* __restrict__ list)
{
  __shared__ ushort_t Ah[2][128 * 64];
  __shared__ ushort_t Bh[2][128 * 64];
  const int t = threadIdx.x;
  const int w = t >> 6, l = t & 63;
  const int li = l & 15, lg = l >> 4;
  const int row0 = blockIdx.x << 7;
  const int wr = (w >> 1) << 6, wc = (w & 1) << 6;

  u32 cand[16][4];
  #pragma unroll
  for (int mi = 0; mi < 16; ++mi) {
    cand[mi][0] = 0xFFFFFFFFu; cand[mi][1] = 0xFFFFFFFFu;
    cand[mi][2] = 0xFFFFFFFFu; cand[mi][3] = 0xFFFFFFFFu;
  }

  f32x4 acc[4][4];
  #pragma unroll
  for (int m = 0; m < 4; ++m)
    #pragma unroll
    for (int n = 0; n < 4; ++n) acc[m][n] = (f32x4){0.f, 0.f, 0.f, 0.f};

  const int Gbase = (w << 6) + l;

#define STAGE(buf_, s_) do {                                                   \
    int kb_ = ((s_) & 7) << 7;                                                 \
    int c0_ = ((s_) >> 3) << 7;                                                \
    _Pragma("unroll")                                                          \
    for (int i = 0; i < 4; ++i) {                                              \
      int G = (i << 8) + Gbase;                      /* granule 0..1023 */     \
      int r = G >> 3, gp = G & 7;                                              \
      int cb = gp ^ (r & 7);                         /* pre-swizzled source */ \
      size_t gA = ((size_t)(row0 + r) << 10) + kb_ + (cb << 4);                \
      size_t gB = ((size_t)(c0_ + r) << 10) + kb_ + (cb << 4);                 \
      int ld = ((i << 8) + (w << 6)) << 4;           /* wave-uniform base */   \
      glds16((const char*)xh + gA, (char*)Ah[buf_] + ld);                      \
      glds16((const char*)eh + gB, (char*)Bh[buf_] + ld);                      \
    }                                                                          \
  } while (0)

  STAGE(0, 0);
  __syncthreads();
  int buf = 0;
  float en0 = 0.f, en1 = 0.f, en2 = 0.f, en3 = 0.f;

  for (int s = 0; s < 128; ++s) {
    if ((s & 7) == 0) {                              // prefetch this tile's norms
      int col0 = (s >> 3) << 7;
      en0 = enorm[col0 + wc + 0  + li];
      en1 = enorm[col0 + wc + 16 + li];
      en2 = enorm[col0 + wc + 32 + li];
      en3 = enorm[col0 + wc + 48 + li];
    }
    if (s != 127) STAGE(buf ^ 1, s + 1);             // loads fly under compute

    #pragma unroll
    for (int kblk = 0; kblk < 2; ++kblk) {
      bf16x8 fah[4], fbh[4];
      #pragma unroll
      for (int m = 0; m < 4; ++m) {
        int r = wr + (m << 4) + li;
        int c = (kblk << 2) + lg;
        int off = (r << 7) + ((c ^ (r & 7)) << 4);   // swizzled read
        fah[m] = *(const bf16x8*)((const char*)Ah[buf] + off);
      }
      #pragma unroll
      for (int n = 0; n < 4; ++n) {
        int r = wc + (n << 4) + li;
        int c = (kblk << 2) + lg;
        int off = (r << 7) + ((c ^ (r & 7)) << 4);
        fbh[n] = *(const bf16x8*)((const char*)Bh[buf] + off);
      }
      #pragma unroll
      for (int m = 0; m < 4; ++m)
        #pragma unroll
        for (int n = 0; n < 4; ++n)
          acc[m][n] = __builtin_amdgcn_mfma_f32_16x16x32_bf16(fah[m], fbh[n], acc[m][n], 0, 0, 0);
    }

    if ((s & 7) == 7) {                              // fold this col-tile
      int col0 = (s >> 3) << 7;
      const u32 colb = (u32)(col0 + wc + li);
      #pragma unroll
      for (int m = 0; m < 4; ++m)
        #pragma unroll
        for (int i = 0; i < 4; ++i) {
          u32 k0 = (__float_as_uint(fmaf(-2.f, acc[m][0][i], en0)) & 0xFFFFF800u) | colb;
          u32 k1 = (__float_as_uint(fmaf(-2.f, acc[m][1][i], en1)) & 0xFFFFF800u) | (colb + 16u);
          u32 k2 = (__float_as_uint(fmaf(-2.f, acc[m][2][i], en2)) & 0xFFFFF800u) | (colb + 32u);
          u32 k3 = (__float_as_uint(fmaf(-2.f, acc[m][3][i], en3)) & 0xFFFFF800u) | (colb + 48u);
          // sort4 ascending
          u32 a = min(k0, k1), b = max(k0, k1);
          u32 c = min(k2, k3), d = max(k2, k3);
          u32 e = min(a, c),  f = max(a, c);
          u32 g = min(b, d),  h = max(b, d);
          u32 q1 = e, q2 = min(f, g), q3 = max(f, g), q4 = h;
          MERGE4(cand[m * 4 + i][0], cand[m * 4 + i][1],
                 cand[m * 4 + i][2], cand[m * 4 + i][3], q1, q2, q3, q4);
          acc[m][0][i] = 0.f; acc[m][1][i] = 0.f;
          acc[m][2][i] = 0.f; acc[m][3][i] = 0.f;
        }
    }
    __syncthreads();                                 // drains staged loads too
    buf ^= 1;
  }
#undef STAGE

  // cross-li merge (16 lanes per row-group; lg preserved under xor<16)
  #pragma unroll
  for (int mi = 0; mi < 16; ++mi) {
    u32 s1 = cand[mi][0], s2 = cand[mi][1], s3 = cand[mi][2], s4 = cand[mi][3];
    #pragma unroll
    for (int off = 1; off <= 8; off <<= 1) {
      u32 o1 = __shfl_xor(s1, off), o2 = __shfl_xor(s2, off);
      u32 o3 = __shfl_xor(s3, off), o4 = __shfl_xor(s4, off);
      MERGE4(s1, s2, s3, s4, o1, o2, o3, o4);
    }
    cand[mi][0] = s1; cand[mi][1] = s2; cand[mi][2] = s3; cand[mi][3] = s4;
  }

  // cross wave-pair merge (w0<-w1, w2<-w3) via LDS, then store row top-4
  u32* ex = (u32*)Ah;                                // [128 rows][4 u32]
  if ((w & 1) == 1 && li == 0) {
    #pragma unroll
    for (int m = 0; m < 4; ++m)
      #pragma unroll
      for (int i = 0; i < 4; ++i) {
        int lrow = wr + (m << 4) + (lg << 2) + i;    // C/D: row=(lane>>4)*4+reg
        uint4 v;
        v.x = cand[m * 4 + i][0]; v.y = cand[m * 4 + i][1];
        v.z = cand[m * 4 + i][2]; v.w = cand[m * 4 + i][3];
        *(uint4*)&ex[lrow << 2] = v;
      }
  }
  __syncthreads();
  if ((w & 1) == 0 && li == 0) {
    #pragma unroll
    for (int m = 0; m < 4; ++m)
      #pragma unroll
      for (int i = 0; i < 4; ++i) {
        int lrow = wr + (m << 4) + (lg << 2) + i;
        const u32* p = &ex[lrow << 2];
        u32 s1 = cand[m * 4 + i][0], s2 = cand[m * 4 + i][1];
        u32 s3 = cand[m * 4 + i][2], s4 = cand[m * 4 + i][3];
        u32 o1 = p[0], o2 = p[1], o3 = p[2], o4 = p[3];
        MERGE4(s1, s2, s3, s4, o1, o2, o3, o4);
        uint4 v; v.x = s1; v.y = s2; v.z = s3; v.w = s4;
        list[row0 + lrow] = v;
      }
  }
}

// ---- finalize argmin: 4 cands/row; fp64 rescore on near-ties ----
// builds cluster histogram AND writes o_idx (was in zq_seg).
__global__ void finalize_kernel(const uint4* __restrict__ list, const float* __restrict__ ze,
                                const float* __restrict__ emb, int* __restrict__ wsidx,
                                float* __restrict__ counts, float* __restrict__ o_idx)
{
  int w = threadIdx.x >> 6, l = threadIdx.x & 63;
  int row = blockIdx.x * 4 + w;                      // grid 16384
  uint4 q = list[row];
  float d1 = __uint_as_float(q.x & 0xFFFFF800u);
  float lim = d1 + TAU;
  bool n2 = (q.y != 0xFFFFFFFFu) && (__uint_as_float(q.y & 0xFFFFF800u) < lim);
  bool n3 = (q.z != 0xFFFFFFFFu) && (__uint_as_float(q.z & 0xFFFFF800u) < lim);
  bool n4 = (q.w != 0xFFFFFFFFu) && (__uint_as_float(q.w & 0xFFFFF800u) < lim);
  int idx;
  if (!(n2 | n3 | n4)) {
    idx = (int)(q.x & 2047u);
  } else {
    double bd = 1e300; int bc = 0x7fffffff;
    const float* xr = ze + (((size_t)row) << 9);
    double xv[8];
    #pragma unroll
    for (int p = 0; p < 8; ++p) xv[p] = (double)xr[(l << 3) + p];
    #pragma unroll
    for (int j = 0; j < 4; ++j) {
      u32 kj = (j == 0) ? q.x : (j == 1) ? q.y : (j == 2) ? q.z : q.w;
      bool ok = (j == 0) || ((kj != 0xFFFFFFFFu) &&
                             (__uint_as_float(kj & 0xFFFFF800u) < lim));
      if (!ok) continue;
      int col = (int)(kj & 2047u);
      const float* er = emb + (((size_t)col) << 9);
      double s = 0.0;
      #pragma unroll
      for (int p = 0; p < 8; ++p) {
        double df = xv[p] - (double)er[(l << 3) + p];
        s += df * df;
      }
      #pragma unroll
      for (int off = 32; off >= 1; off >>= 1) s += __shfl_xor(s, off);
      if (s < bd || (s == bd && col < bc)) { bd = s; bc = col; }
    }
    idx = bc;
  }
  if (l == 0) {
    wsidx[row] = idx;
    o_idx[row] = (float)idx;
    atomicAdd(&counts[idx], 1.0f);
  }
}

// ---- single-block scan: offsets/cursor/chunks + fused d1 (ncs/inv/o_ncs) ----
__global__ void scan_kernel(const float* __restrict__ counts, const float* __restrict__ cs,
                            u32* __restrict__ offsets, u32* __restrict__ cursor,
                            u32* __restrict__ chunkinfo, u32* __restrict__ ntotal,
                            float* __restrict__ o_ncs, float* __restrict__ inv)
{
  int t = threadIdx.x;                               // 1 block, 256 threads
  int c[8]; int s = 0;
  float ncs[8]; float nsum = 0.0f;
  #pragma unroll
  for (int i = 0; i < 8; ++i) {
    int k = t * 8 + i;
    c[i] = (int)counts[k]; s += c[i];
    float v = 0.99f * cs[k] + 0.01f * counts[k];
    ncs[i] = v; o_ncs[k] = v; nsum += v;
  }
  __shared__ int ts[256];
  __shared__ float red[256];
  red[t] = nsum;
  ts[t] = s; __syncthreads();
  for (int off = 1; off < 256; off <<= 1) {
    int v = (t >= off) ? ts[t - off] : 0;
    __syncthreads();
    ts[t] += v;
    __syncthreads();
  }
  // ncs total (d1's tree reduce shape)
  for (int h = 128; h >= 1; h >>= 1) { if (t < h) red[t] += red[t + h]; __syncthreads(); }
  float n = red[0];
  float denom = n + 2048.0f * 1e-5f;
  #pragma unroll
  for (int i = 0; i < 8; ++i) {
    float sm = (ncs[i] + 1e-5f) / denom * n;
    inv[t * 8 + i] = 1.0f / sm;
  }
  int run = ts[t] - s;                               // exclusive prefix
  int nch[8]; int ns = 0;
  #pragma unroll
  for (int i = 0; i < 8; ++i) {
    offsets[t * 8 + i] = (u32)run;
    cursor[t * 8 + i] = 0;
    run += c[i];
    nch[i] = (c[i] + CHUNK - 1) / CHUNK;
    ns += nch[i];
  }
  __shared__ int ts2[256];
  ts2[t] = ns; __syncthreads();
  for (int off = 1; off < 256; off <<= 1) {
    int v = (t >= off) ? ts2[t - off] : 0;
    __syncthreads();
    ts2[t] += v;
    __syncthreads();
  }
  int cb = ts2[t] - ns;
  #pragma unroll
  for (int i = 0; i < 8; ++i)
    for (int cc = 0; cc < nch[i]; ++cc)
      chunkinfo[cb++] = (u32)(t * 8 + i) | ((u32)cc << 11);
  if (t == 255) *ntotal = (u32)ts2[255];
}

// ---- merged scatter + selective esum zero ----
__global__ void scatter_zero_kernel(const int* __restrict__ wsidx, const u32* __restrict__ offsets,
                                    u32* __restrict__ cursor, u32* __restrict__ sorted,
                                    const float* __restrict__ counts, float* __restrict__ esum)
{
  int bx = blockIdx.x;                               // grid 2304
  int t = threadIdx.x;
  if (bx < 256) {
    int row = bx * 256 + t;
    int idx = wsidx[row];
    u32 pos = atomicAdd(&cursor[idx], 1u);
    sorted[offsets[idx] + pos] = (u32)row;
  } else {
    int k = bx - 256;                                // 0..2047
    float c = counts[k];
    if (c == 0.0f || c > (float)CHUNK) {
      esum[((size_t)k << 9) + t] = 0.0f;
      esum[((size_t)k << 9) + 256 + t] = 0.0f;
    }
  }
}

// ---- per-chunk fused: z_q write, loss, segment sum + d2 (EMA+embedding) ----
// single-chunk clusters: write o_nea/o_emb directly from register colsums;
// multi-chunk: atomicAdd into esum scratch (o_emb section), tail fixes.
__global__ __launch_bounds__(256)
void zq_seg_kernel(const float* __restrict__ ze, const float* __restrict__ emb,
                   const float* __restrict__ ea, const float* __restrict__ inv,
                   const u32* __restrict__ offsets, const float* __restrict__ counts,
                   const u32* __restrict__ sorted, const u32* __restrict__ chunkinfo,
                   const u32* __restrict__ ntotal, float* __restrict__ o_zq,
                   float* __restrict__ esum, float* __restrict__ o_nea,
                   float* __restrict__ lossws)
{
  int cid = blockIdx.x;                              // grid MAXCHUNK
  if (cid >= (int)*ntotal) return;
  u32 rec = chunkinfo[cid];
  int k = rec & 2047, c = (int)(rec >> 11);
  int ctotal = (int)counts[k];
  int base = (int)offsets[k] + c * CHUNK;
  int cnt = min(ctotal - c * CHUNK, CHUNK);
  bool multi = ctotal > CHUNK;
  int t = threadIdx.x, w = t >> 6, l = t & 63;
  __shared__ u32 srow[CHUNK];
  __shared__ float sacc[4 * 512];
  __shared__ float sloss[4];
  if (t < cnt) srow[t] = sorted[base + t];
  __syncthreads();
  const float4* e4 = (const float4*)(emb + ((size_t)k << 9));
  float4 ev0 = e4[l * 2], ev1 = e4[l * 2 + 1];
  float a0x=0,a0y=0,a0z=0,a0w=0,a1x=0,a1y=0,a1z=0,a1w=0;
  float lacc = 0.f;
  for (int r = w; r < cnt; r += 4) {
    int row = (int)srow[r];
    const float4* z4 = (const float4*)(ze + ((size_t)row << 9));
    float4 zv0 = z4[l * 2], zv1 = z4[l * 2 + 1];
    float4 q0, q1;
    q0.x = zv0.x + (ev0.x - zv0.x);
    q0.y = zv0.y + (ev0.y - zv0.y);
    q0.z = zv0.z + (ev0.z - zv0.z);
    q0.w = zv0.w + (ev0.w - zv0.w);
    q1.x = zv1.x + (ev1.x - zv1.x);
    q1.y = zv1.y + (ev1.y - zv1.y);
    q1.z = zv1.z + (ev1.z - zv1.z);
    q1.w = zv1.w + (ev1.w - zv1.w);
    float4* zq4 = (float4*)(o_zq + ((size_t)row << 9));
    zq4[l * 2] = q0; zq4[l * 2 + 1] = q1;
    float dx = zv0.x - q0.x, dy = zv0.y - q0.y, dz = zv0.z - q0.z, dw = zv0.w - q0.w;
    lacc += dx*dx + dy*dy + dz*dz + dw*dw;
    dx = zv1.x - q1.x; dy = zv1.y - q1.y; dz = zv1.z - q1.z; dw = zv1.w - q1.w;
    lacc += dx*dx + dy*dy + dz*dz + dw*dw;
    a0x += zv0.x; a0y += zv0.y; a0z += zv0.z; a0w += zv0.w;
    a1x += zv1.x; a1y += zv1.y; a1z += zv1.z; a1w += zv1.w;
  }
  #pragma unroll
  for (int off = 32; off >= 1; off >>= 1) lacc += __shfl_xor(lacc, off);
  if (l == 0) sloss[w] = lacc;
  float* sa = sacc + w * 512 + l * 8;
  sa[0]=a0x; sa[1]=a0y; sa[2]=a0z; sa[3]=a0w; sa[4]=a1x; sa[5]=a1y; sa[6]=a1z; sa[7]=a1w;
  __syncthreads();
  float ikv = inv[k];
  #pragma unroll
  for (int j = 0; j < 2; ++j) {
    int col = t * 2 + j;
    float v = sacc[col] + sacc[512 + col] + sacc[1024 + col] + sacc[1536 + col];
    if (multi) {
      atomicAdd(&esum[((size_t)k << 9) + col], v);
    } else {
      // fused d2: nea = 0.99*ea + 0.01*esum; emb_new = nea * inv[k]
      float nea = 0.99f * ea[((size_t)k << 9) + col] + 0.01f * v;
      o_nea[((size_t)k << 9) + col] = nea;
      esum[((size_t)k << 9) + col] = nea * ikv;      // esum aliases o_emb
    }
  }
  if (t == 0) atomicAdd(lossws, sloss[0] + sloss[1] + sloss[2] + sloss[3]);
}

// ---- tail: empty + multi-chunk clusters d2, plus o_loss ----
__global__ void tail_kernel(const float* __restrict__ counts, const float* __restrict__ ea,
                            const float* __restrict__ inv, float* __restrict__ o_emb,
                            float* __restrict__ o_nea, const float* __restrict__ lossws,
                            float* __restrict__ o_loss)
{
  int k = blockIdx.x;                                // grid 2048
  int t = threadIdx.x;
  if (k == 0 && t == 0) o_loss[0] = lossws[0] * 1.25f / 33554432.0f;
  float c = counts[k];
  bool empty = (c == 0.0f), multi = (c > (float)CHUNK);
  if (!(empty | multi)) return;
  float ikv = inv[k];
  #pragma unroll
  for (int j = 0; j < 2; ++j) {
    int col = t + (j << 8);
    size_t p = ((size_t)k << 9) + col;
    float es = empty ? 0.0f : o_emb[p];              // multi: raw atomic esum
    float nea = 0.99f * ea[p] + 0.01f * es;
    o_nea[p] = nea;
    o_emb[p] = nea * ikv;
  }
}

extern "C" void kernel_launch(void* const* d_in, const int* in_sizes, int n_in,
                              void* d_out, int out_size, void* d_ws, size_t ws_size,
                              hipStream_t stream)
{
  const float* ze  = (const float*)d_in[0];
  const float* emb = (const float*)d_in[1];
  const float* cs  = (const float*)d_in[2];
  const float* ea  = (const float*)d_in[3];
  float* out = (float*)d_out;
  float* o_zq   = out + OFF_ZQ;
  float* o_idx  = out + OFF_IDX;
  float* o_loss = out + OFF_LOSS;
  float* o_emb  = out + OFF_EMB;
  float* o_ncs  = out + OFF_NCS;
  float* o_nea  = out + OFF_NEA;
  // d_out self-scratch: bf16 z_e lives in the z_q section (64 MB, consumed
  // by dist_gemm before zq_seg overwrites it). o_emb doubles as esum scratch.
  ushort_t* xh = (ushort_t*)d_out;
  // workspace layout
  char* ws = (char*)d_ws;
  ushort_t* ehp = (ushort_t*)ws;                     // 2 MB
  int* wsidx    = (int*)(ws + 2097152);              // 256 KB
  float* counts = (float*)(ws + 2097152 + 262144);   // 8 KB
  float* enorm  = counts + 2048;                     // 8 KB
  float* inv    = enorm + 2048;                      // 8 KB
  float* lossws = inv + 2048;                        // 4 B (+pad)
  u32* offsets  = (u32*)(lossws + 64);               // 8 KB
  u32* cursor   = offsets + 2048;                    // 8 KB
  u32* sorted   = cursor + 2048;                     // 256 KB
  u32* chunkinfo= sorted + 65536;                    // 10 KB
  u32* ntotal   = chunkinfo + MAXCHUNK;              // 4 B
  uint4* list   = (uint4*)(ws + 3145728);            // 1 MB, [65536] uint4

  prep_kernel<<<8704, 256, 0, stream>>>(ze, emb, xh, ehp, enorm, counts, lossws);
  dist_gemm<<<512, 256, 0, stream>>>(xh, ehp, enorm, list);
  finalize_kernel<<<16384, 256, 0, stream>>>(list, ze, emb, wsidx, counts, o_idx);
  scan_kernel<<<1, 256, 0, stream>>>(counts, cs, offsets, cursor, chunkinfo, ntotal,
                                     o_ncs, inv);
  scatter_zero_kernel<<<2304, 256, 0, stream>>>(wsidx, offsets, cursor, sorted,
                                                counts, o_emb);
  zq_seg_kernel<<<MAXCHUNK, 256, 0, stream>>>(ze, emb, ea, inv, offsets, counts, sorted,
                                              chunkinfo, ntotal, o_zq, o_emb, o_nea, lossws);
  tail_kernel<<<2048, 256, 0, stream>>>(counts, ea, inv, o_emb, o_nea, lossws, o_loss);
}

// Round 11
// 332.987 us; speedup vs baseline: 1.2353x; 1.0073x over previous
//
#include <hip/hip_runtime.h>

typedef unsigned short ushort_t;
typedef unsigned int u32;
typedef unsigned long long u64;
typedef __attribute__((ext_vector_type(8))) short bf16x8;   // 8 bf16 in 4 VGPRs
typedef __attribute__((ext_vector_type(4))) float f32x4;

#define N_ROWS 65536
#define K_EMB  2048
#define D_DIM  512
// d_out float offsets (outputs concatenated in return order)
#define OFF_ZQ   0
#define OFF_IDX  33554432
#define OFF_LOSS 33619968
#define OFF_EMB  33619969
#define OFF_NCS  34668545
#define OFF_NEA  34670593
#define TAU 1.5f
#define CHUNK 128
#define MAXCHUNK 2560

__device__ __forceinline__ ushort_t f2bf(float f) {
  u32 u = __float_as_uint(f);
  u32 r = (u + 0x7fffu + ((u >> 16) & 1u)) >> 16;   // RNE
  return (ushort_t)r;
}
__device__ __forceinline__ void glds16(const void* g, void* l) {
  __builtin_amdgcn_global_load_lds((const __attribute__((address_space(1))) u32*)g,
                                   (__attribute__((address_space(3))) u32*)l, 16, 0, 0);
}

// merge two ascending quads (s,o), keep 4 smallest ascending in s
#define MERGE4(s1,s2,s3,s4,o1,o2,o3,o4) do {                        \
    u32 x1 = min(s1,o4), x2 = min(s2,o3), x3 = min(s3,o2), x4 = min(s4,o1); \
    u32 t1 = min(x1,x3), t3 = max(x1,x3), t2 = min(x2,x4), t4 = max(x2,x4); \
    s1 = min(t1,t2); s2 = max(t1,t2); s3 = min(t3,t4); s4 = max(t3,t4);     \
  } while (0)

// ---- merged prep: blocks 0..511 = embedding split + norms; 512.. = z_e split ----
__global__ void prep_kernel(const float* __restrict__ ze, const float* __restrict__ emb,
                            ushort_t* __restrict__ xh, ushort_t* __restrict__ eh,
                            float* __restrict__ enorm, float* __restrict__ counts,
                            float* __restrict__ lossws)
{
  int bx = blockIdx.x;
  int t = threadIdx.x;
  if (bx < 512) {
    int w = t >> 6, l = t & 63;
    int k = bx * 4 + w;                              // 2048 rows
    const float4* row = (const float4*)(emb + (size_t)k * D_DIM);
    float4 a = row[l * 2], b = row[l * 2 + 1];
    ushort4 h0, h1;
    h0.x = f2bf(a.x); h0.y = f2bf(a.y); h0.z = f2bf(a.z); h0.w = f2bf(a.w);
    h1.x = f2bf(b.x); h1.y = f2bf(b.y); h1.z = f2bf(b.z); h1.w = f2bf(b.w);
    ((ushort4*)(eh + (size_t)k * D_DIM))[l * 2] = h0;
    ((ushort4*)(eh + (size_t)k * D_DIM))[l * 2 + 1] = h1;
    float s = a.x*a.x + a.y*a.y + a.z*a.z + a.w*a.w + b.x*b.x + b.y*b.y + b.z*b.z + b.w*b.w;
    #pragma unroll
    for (int off = 32; off >= 1; off >>= 1) s += __shfl_xor(s, off);
    if (l == 0) enorm[k] = s;
  } else {
    int gid = (bx - 512) * 256 + t;                  // 8192-block portion
    const float4* zin = (const float4*)ze;
    ushort4* xh4 = (ushort4*)xh;
    for (int g = gid; g < (N_ROWS * D_DIM / 4); g += 8192 * 256) {
      float4 v = zin[g];
      ushort4 h;
      h.x = f2bf(v.x); h.y = f2bf(v.y); h.z = f2bf(v.z); h.w = f2bf(v.w);
      xh4[g] = h;
    }
    if (gid < K_EMB) counts[gid] = 0.0f;
    if (gid == 0) lossws[0] = 0.0f;
  }
}

// ---- main distance GEMM: round-9 structure + VALU trim (hoisted addressing) ----
// grid 512: each block = 128 rows x all 2048 cols, 16 col-tiles, BK=64.
// 4 waves (2x2), wave tile 64x64, 16x16x32 MFMA, proven ^(r&7) 128B-row LDS
// swizzle, global_load_lds, 2x32KB dbuf, STAGE(s+1) before compute(s), one
// __syncthreads per step. NEW: all ds_read offsets precomputed (per-lane
// consts); staged global addresses = per-lane u32 base + scalar(kit,ct) ->
// 1 v_add per load instead of full 64-bit recompute.
__global__ __launch_bounds__(256, 2)
void dist_gemm(const ushort_t* __restrict__ xh, const ushort_t* __restrict__ eh,
               const float* __restrict__ enorm, uint4* __restrict__ list)
{
  __shared__ ushort_t Ah[2][128 * 64];
  __shared__ ushort_t Bh[2][128 * 64];
  const int t = threadIdx.x;
  const int w = t >> 6, l = t & 63;
  const int li = l & 15, lg = l >> 4;
  const int row0 = blockIdx.x << 7;
  const int wr = (w >> 1) << 6, wc = (w & 1) << 6;

  // per-lane constant staging bases (u32 byte offsets) and LDS dests
  u32 offAb[4], offBb[4], ldso[4];
  #pragma unroll
  for (int i = 0; i < 4; ++i) {
    int G = (i << 8) + (w << 6) + l;                 // granule 0..1023
    int r = G >> 3, gp = G & 7;
    int cb = gp ^ (r & 7);                           // pre-swizzled source
    offAb[i] = ((u32)(row0 + r) << 10) + ((u32)cb << 4);
    offBb[i] = ((u32)r << 10) + ((u32)cb << 4);
    ldso[i] = ((u32)((i << 8) + (w << 6))) << 4;     // wave-uniform LDS base
  }
  // per-lane constant ds_read byte offsets (swizzled)
  int aoff[2][4], boff[2][4];
  #pragma unroll
  for (int kblk = 0; kblk < 2; ++kblk) {
    #pragma unroll
    for (int m = 0; m < 4; ++m) {
      int r = wr + (m << 4) + li;
      int c = (kblk << 2) + lg;
      aoff[kblk][m] = (r << 7) + ((c ^ (r & 7)) << 4);
      r = wc + (m << 4) + li;
      boff[kblk][m] = (r << 7) + ((c ^ (r & 7)) << 4);
    }
  }

  u32 cand[16][4];
  #pragma unroll
  for (int mi = 0; mi < 16; ++mi) {
    cand[mi][0] = 0xFFFFFFFFu; cand[mi][1] = 0xFFFFFFFFu;
    cand[mi][2] = 0xFFFFFFFFu; cand[mi][3] = 0xFFFFFFFFu;
  }

  f32x4 acc[4][4];
  #pragma unroll
  for (int m = 0; m < 4; ++m)
    #pragma unroll
    for (int n = 0; n < 4; ++n) acc[m][n] = (f32x4){0.f, 0.f, 0.f, 0.f};

  // stage step s_ into buffer buf_: scalar part = kit*128 (+ ct*131072 for B)
#define STAGE(buf_, s_) do {                                                   \
    u32 sa_ = (u32)(((s_) & 7) << 7);                                          \
    u32 sb_ = (u32)((((s_) >> 3) << 17) + (((s_) & 7) << 7));                  \
    _Pragma("unroll")                                                          \
    for (int i = 0; i < 4; ++i) {                                              \
      glds16((const char*)xh + (offAb[i] + sa_), (char*)Ah[buf_] + ldso[i]);   \
      glds16((const char*)eh + (offBb[i] + sb_), (char*)Bh[buf_] + ldso[i]);   \
    }                                                                          \
  } while (0)

  STAGE(0, 0);
  __syncthreads();
  int buf = 0;
  float en0 = 0.f, en1 = 0.f, en2 = 0.f, en3 = 0.f;

  for (int s = 0; s < 128; ++s) {
    if ((s & 7) == 0) {                              // prefetch this tile's norms
      int col0 = (s >> 3) << 7;
      en0 = enorm[col0 + wc + 0  + li];
      en1 = enorm[col0 + wc + 16 + li];
      en2 = enorm[col0 + wc + 32 + li];
      en3 = enorm[col0 + wc + 48 + li];
    }
    if (s != 127) STAGE(buf ^ 1, s + 1);             // loads fly under compute

    #pragma unroll
    for (int kblk = 0; kblk < 2; ++kblk) {
      bf16x8 fah[4], fbh[4];
      #pragma unroll
      for (int m = 0; m < 4; ++m)
        fah[m] = *(const bf16x8*)((const char*)Ah[buf] + aoff[kblk][m]);
      #pragma unroll
      for (int n = 0; n < 4; ++n)
        fbh[n] = *(const bf16x8*)((const char*)Bh[buf] + boff[kblk][n]);
      #pragma unroll
      for (int m = 0; m < 4; ++m)
        #pragma unroll
        for (int n = 0; n < 4; ++n)
          acc[m][n] = __builtin_amdgcn_mfma_f32_16x16x32_bf16(fah[m], fbh[n], acc[m][n], 0, 0, 0);
    }

    if ((s & 7) == 7) {                              // fold this col-tile
      int col0 = (s >> 3) << 7;
      const u32 colb = (u32)(col0 + wc + li);
      #pragma unroll
      for (int m = 0; m < 4; ++m)
        #pragma unroll
        for (int i = 0; i < 4; ++i) {
          u32 k0 = (__float_as_uint(fmaf(-2.f, acc[m][0][i], en0)) & 0xFFFFF800u) | colb;
          u32 k1 = (__float_as_uint(fmaf(-2.f, acc[m][1][i], en1)) & 0xFFFFF800u) | (colb + 16u);
          u32 k2 = (__float_as_uint(fmaf(-2.f, acc[m][2][i], en2)) & 0xFFFFF800u) | (colb + 32u);
          u32 k3 = (__float_as_uint(fmaf(-2.f, acc[m][3][i], en3)) & 0xFFFFF800u) | (colb + 48u);
          // sort4 ascending
          u32 a = min(k0, k1), b = max(k0, k1);
          u32 c = min(k2, k3), d = max(k2, k3);
          u32 e = min(a, c),  f = max(a, c);
          u32 g = min(b, d),  h = max(b, d);
          u32 q1 = e, q2 = min(f, g), q3 = max(f, g), q4 = h;
          MERGE4(cand[m * 4 + i][0], cand[m * 4 + i][1],
                 cand[m * 4 + i][2], cand[m * 4 + i][3], q1, q2, q3, q4);
          acc[m][0][i] = 0.f; acc[m][1][i] = 0.f;
          acc[m][2][i] = 0.f; acc[m][3][i] = 0.f;
        }
    }
    __syncthreads();                                 // drains staged loads too
    buf ^= 1;
  }
#undef STAGE

  // cross-li merge (16 lanes per row-group; lg preserved under xor<16)
  #pragma unroll
  for (int mi = 0; mi < 16; ++mi) {
    u32 s1 = cand[mi][0], s2 = cand[mi][1], s3 = cand[mi][2], s4 = cand[mi][3];
    #pragma unroll
    for (int off = 1; off <= 8; off <<= 1) {
      u32 o1 = __shfl_xor(s1, off), o2 = __shfl_xor(s2, off);
      u32 o3 = __shfl_xor(s3, off), o4 = __shfl_xor(s4, off);
      MERGE4(s1, s2, s3, s4, o1, o2, o3, o4);
    }
    cand[mi][0] = s1; cand[mi][1] = s2; cand[mi][2] = s3; cand[mi][3] = s4;
  }

  // cross wave-pair merge (w0<-w1, w2<-w3) via LDS, then store row top-4
  u32* ex = (u32*)Ah;                                // [128 rows][4 u32]
  if ((w & 1) == 1 && li == 0) {
    #pragma unroll
    for (int m = 0; m < 4; ++m)
      #pragma unroll
      for (int i = 0; i < 4; ++i) {
        int lrow = wr + (m << 4) + (lg << 2) + i;    // C/D: row=(lane>>4)*4+reg
        uint4 v;
        v.x = cand[m * 4 + i][0]; v.y = cand[m * 4 + i][1];
        v.z = cand[m * 4 + i][2]; v.w = cand[m * 4 + i][3];
        *(uint4*)&ex[lrow << 2] = v;
      }
  }
  __syncthreads();
  if ((w & 1) == 0 && li == 0) {
    #pragma unroll
    for (int m = 0; m < 4; ++m)
      #pragma unroll
      for (int i = 0; i < 4; ++i) {
        int lrow = wr + (m << 4) + (lg << 2) + i;
        const u32* p = &ex[lrow << 2];
        u32 s1 = cand[m * 4 + i][0], s2 = cand[m * 4 + i][1];
        u32 s3 = cand[m * 4 + i][2], s4 = cand[m * 4 + i][3];
        u32 o1 = p[0], o2 = p[1], o3 = p[2], o4 = p[3];
        MERGE4(s1, s2, s3, s4, o1, o2, o3, o4);
        uint4 v; v.x = s1; v.y = s2; v.z = s3; v.w = s4;
        list[row0 + lrow] = v;
      }
  }
}

// ---- finalize argmin: 4 cands/row; fp64 rescore on near-ties ----
// builds cluster histogram AND writes o_idx.
__global__ void finalize_kernel(const uint4* __restrict__ list, const float* __restrict__ ze,
                                const float* __restrict__ emb, int* __restrict__ wsidx,
                                float* __restrict__ counts, float* __restrict__ o_idx)
{
  int w = threadIdx.x >> 6, l = threadIdx.x & 63;
  int row = blockIdx.x * 4 + w;                      // grid 16384
  uint4 q = list[row];
  float d1 = __uint_as_float(q.x & 0xFFFFF800u);
  float lim = d1 + TAU;
  bool n2 = (q.y != 0xFFFFFFFFu) && (__uint_as_float(q.y & 0xFFFFF800u) < lim);
  bool n3 = (q.z != 0xFFFFFFFFu) && (__uint_as_float(q.z & 0xFFFFF800u) < lim);
  bool n4 = (q.w != 0xFFFFFFFFu) && (__uint_as_float(q.w & 0xFFFFF800u) < lim);
  int idx;
  if (!(n2 | n3 | n4)) {
    idx = (int)(q.x & 2047u);
  } else {
    double bd = 1e300; int bc = 0x7fffffff;
    const float* xr = ze + (((size_t)row) << 9);
    double xv[8];
    #pragma unroll
    for (int p = 0; p < 8; ++p) xv[p] = (double)xr[(l << 3) + p];
    #pragma unroll
    for (int j = 0; j < 4; ++j) {
      u32 kj = (j == 0) ? q.x : (j == 1) ? q.y : (j == 2) ? q.z : q.w;
      bool ok = (j == 0) || ((kj != 0xFFFFFFFFu) &&
                             (__uint_as_float(kj & 0xFFFFF800u) < lim));
      if (!ok) continue;
      int col = (int)(kj & 2047u);
      const float* er = emb + (((size_t)col) << 9);
      double s = 0.0;
      #pragma unroll
      for (int p = 0; p < 8; ++p) {
        double df = xv[p] - (double)er[(l << 3) + p];
        s += df * df;
      }
      #pragma unroll
      for (int off = 32; off >= 1; off >>= 1) s += __shfl_xor(s, off);
      if (s < bd || (s == bd && col < bc)) { bd = s; bc = col; }
    }
    idx = bc;
  }
  if (l == 0) {
    wsidx[row] = idx;
    o_idx[row] = (float)idx;
    atomicAdd(&counts[idx], 1.0f);
  }
}

// ---- single-block scan: offsets/cursor/chunks + fused d1 (ncs/inv/o_ncs) ----
__global__ void scan_kernel(const float* __restrict__ counts, const float* __restrict__ cs,
                            u32* __restrict__ offsets, u32* __restrict__ cursor,
                            u32* __restrict__ chunkinfo, u32* __restrict__ ntotal,
                            float* __restrict__ o_ncs, float* __restrict__ inv)
{
  int t = threadIdx.x;                               // 1 block, 256 threads
  int c[8]; int s = 0;
  float ncs[8]; float nsum = 0.0f;
  #pragma unroll
  for (int i = 0; i < 8; ++i) {
    int k = t * 8 + i;
    c[i] = (int)counts[k]; s += c[i];
    float v = 0.99f * cs[k] + 0.01f * counts[k];
    ncs[i] = v; o_ncs[k] = v; nsum += v;
  }
  __shared__ int ts[256];
  __shared__ float red[256];
  red[t] = nsum;
  ts[t] = s; __syncthreads();
  for (int off = 1; off < 256; off <<= 1) {
    int v = (t >= off) ? ts[t - off] : 0;
    __syncthreads();
    ts[t] += v;
    __syncthreads();
  }
  for (int h = 128; h >= 1; h >>= 1) { if (t < h) red[t] += red[t + h]; __syncthreads(); }
  float n = red[0];
  float denom = n + 2048.0f * 1e-5f;
  #pragma unroll
  for (int i = 0; i < 8; ++i) {
    float sm = (ncs[i] + 1e-5f) / denom * n;
    inv[t * 8 + i] = 1.0f / sm;
  }
  int run = ts[t] - s;                               // exclusive prefix
  int nch[8]; int ns = 0;
  #pragma unroll
  for (int i = 0; i < 8; ++i) {
    offsets[t * 8 + i] = (u32)run;
    cursor[t * 8 + i] = 0;
    run += c[i];
    nch[i] = (c[i] + CHUNK - 1) / CHUNK;
    ns += nch[i];
  }
  __shared__ int ts2[256];
  ts2[t] = ns; __syncthreads();
  for (int off = 1; off < 256; off <<= 1) {
    int v = (t >= off) ? ts2[t - off] : 0;
    __syncthreads();
    ts2[t] += v;
    __syncthreads();
  }
  int cb = ts2[t] - ns;
  #pragma unroll
  for (int i = 0; i < 8; ++i)
    for (int cc = 0; cc < nch[i]; ++cc)
      chunkinfo[cb++] = (u32)(t * 8 + i) | ((u32)cc << 11);
  if (t == 255) *ntotal = (u32)ts2[255];
}

// ---- merged scatter + selective esum zero ----
__global__ void scatter_zero_kernel(const int* __restrict__ wsidx, const u32* __restrict__ offsets,
                                    u32* __restrict__ cursor, u32* __restrict__ sorted,
                                    const float* __restrict__ counts, float* __restrict__ esum)
{
  int bx = blockIdx.x;                               // grid 2304
  int t = threadIdx.x;
  if (bx < 256) {
    int row = bx * 256 + t;
    int idx = wsidx[row];
    u32 pos = atomicAdd(&cursor[idx], 1u);
    sorted[offsets[idx] + pos] = (u32)row;
  } else {
    int k = bx - 256;                                // 0..2047
    float c = counts[k];
    if (c == 0.0f || c > (float)CHUNK) {
      esum[((size_t)k << 9) + t] = 0.0f;
      esum[((size_t)k << 9) + 256 + t] = 0.0f;
    }
  }
}

// ---- per-chunk fused: z_q write, loss, segment sum + d2 (EMA+embedding) ----
__global__ __launch_bounds__(256)
void zq_seg_kernel(const float* __restrict__ ze, const float* __restrict__ emb,
                   const float* __restrict__ ea, const float* __restrict__ inv,
                   const u32* __restrict__ offsets, const float* __restrict__ counts,
                   const u32* __restrict__ sorted, const u32* __restrict__ chunkinfo,
                   const u32* __restrict__ ntotal, float* __restrict__ o_zq,
                   float* __restrict__ esum, float* __restrict__ o_nea,
                   float* __restrict__ lossws)
{
  int cid = blockIdx.x;                              // grid MAXCHUNK
  if (cid >= (int)*ntotal) return;
  u32 rec = chunkinfo[cid];
  int k = rec & 2047, c = (int)(rec >> 11);
  int ctotal = (int)counts[k];
  int base = (int)offsets[k] + c * CHUNK;
  int cnt = min(ctotal - c * CHUNK, CHUNK);
  bool multi = ctotal > CHUNK;
  int t = threadIdx.x, w = t >> 6, l = t & 63;
  __shared__ u32 srow[CHUNK];
  __shared__ float sacc[4 * 512];
  __shared__ float sloss[4];
  if (t < cnt) srow[t] = sorted[base + t];
  __syncthreads();
  const float4* e4 = (const float4*)(emb + ((size_t)k << 9));
  float4 ev0 = e4[l * 2], ev1 = e4[l * 2 + 1];
  float a0x=0,a0y=0,a0z=0,a0w=0,a1x=0,a1y=0,a1z=0,a1w=0;
  float lacc = 0.f;
  for (int r = w; r < cnt; r += 4) {
    int row = (int)srow[r];
    const float4* z4 = (const float4*)(ze + ((size_t)row << 9));
    float4 zv0 = z4[l * 2], zv1 = z4[l * 2 + 1];
    float4 q0, q1;
    q0.x = zv0.x + (ev0.x - zv0.x);
    q0.y = zv0.y + (ev0.y - zv0.y);
    q0.z = zv0.z + (ev0.z - zv0.z);
    q0.w = zv0.w + (ev0.w - zv0.w);
    q1.x = zv1.x + (ev1.x - zv1.x);
    q1.y = zv1.y + (ev1.y - zv1.y);
    q1.z = zv1.z + (ev1.z - zv1.z);
    q1.w = zv1.w + (ev1.w - zv1.w);
    float4* zq4 = (float4*)(o_zq + ((size_t)row << 9));
    zq4[l * 2] = q0; zq4[l * 2 + 1] = q1;
    float dx = zv0.x - q0.x, dy = zv0.y - q0.y, dz = zv0.z - q0.z, dw = zv0.w - q0.w;
    lacc += dx*dx + dy*dy + dz*dz + dw*dw;
    dx = zv1.x - q1.x; dy = zv1.y - q1.y; dz = zv1.z - q1.z; dw = zv1.w - q1.w;
    lacc += dx*dx + dy*dy + dz*dz + dw*dw;
    a0x += zv0.x; a0y += zv0.y; a0z += zv0.z; a0w += zv0.w;
    a1x += zv1.x; a1y += zv1.y; a1z += zv1.z; a1w += zv1.w;
  }
  #pragma unroll
  for (int off = 32; off >= 1; off >>= 1) lacc += __shfl_xor(lacc, off);
  if (l == 0) sloss[w] = lacc;
  float* sa = sacc + w * 512 + l * 8;
  sa[0]=a0x; sa[1]=a0y; sa[2]=a0z; sa[3]=a0w; sa[4]=a1x; sa[5]=a1y; sa[6]=a1z; sa[7]=a1w;
  __syncthreads();
  float ikv = inv[k];
  #pragma unroll
  for (int j = 0; j < 2; ++j) {
    int col = t * 2 + j;
    float v = sacc[col] + sacc[512 + col] + sacc[1024 + col] + sacc[1536 + col];
    if (multi) {
      atomicAdd(&esum[((size_t)k << 9) + col], v);
    } else {
      float nea = 0.99f * ea[((size_t)k << 9) + col] + 0.01f * v;
      o_nea[((size_t)k << 9) + col] = nea;
      esum[((size_t)k << 9) + col] = nea * ikv;      // esum aliases o_emb
    }
  }
  if (t == 0) atomicAdd(lossws, sloss[0] + sloss[1] + sloss[2] + sloss[3]);
}

// ---- tail: empty + multi-chunk clusters d2, plus o_loss ----
__global__ void tail_kernel(const float* __restrict__ counts, const float* __restrict__ ea,
                            const float* __restrict__ inv, float* __restrict__ o_emb,
                            float* __restrict__ o_nea, const float* __restrict__ lossws,
                            float* __restrict__ o_loss)
{
  int k = blockIdx.x;                                // grid 2048
  int t = threadIdx.x;
  if (k == 0 && t == 0) o_loss[0] = lossws[0] * 1.25f / 33554432.0f;
  float c = counts[k];
  bool empty = (c == 0.0f), multi = (c > (float)CHUNK);
  if (!(empty | multi)) return;
  float ikv = inv[k];
  #pragma unroll
  for (int j = 0; j < 2; ++j) {
    int col = t + (j << 8);
    size_t p = ((size_t)k << 9) + col;
    float es = empty ? 0.0f : o_emb[p];              // multi: raw atomic esum
    float nea = 0.99f * ea[p] + 0.01f * es;
    o_nea[p] = nea;
    o_emb[p] = nea * ikv;
  }
}

extern "C" void kernel_launch(void* const* d_in, const int* in_sizes, int n_in,
                              void* d_out, int out_size, void* d_ws, size_t ws_size,
                              hipStream_t stream)
{
  const float* ze  = (const float*)d_in[0];
  const float* emb = (const float*)d_in[1];
  const float* cs  = (const float*)d_in[2];
  const float* ea  = (const float*)d_in[3];
  float* out = (float*)d_out;
  float* o_zq   = out + OFF_ZQ;
  float* o_idx  = out + OFF_IDX;
  float* o_loss = out + OFF_LOSS;
  float* o_emb  = out + OFF_EMB;
  float* o_ncs  = out + OFF_NCS;
  float* o_nea  = out + OFF_NEA;
  // d_out self-scratch: bf16 z_e lives in the z_q section (64 MB, consumed
  // by dist_gemm before zq_seg overwrites it). o_emb doubles as esum scratch.
  ushort_t* xh = (ushort_t*)d_out;
  // workspace layout
  char* ws = (char*)d_ws;
  ushort_t* ehp = (ushort_t*)ws;                     // 2 MB
  int* wsidx    = (int*)(ws + 2097152);              // 256 KB
  float* counts = (float*)(ws + 2097152 + 262144);   // 8 KB
  float* enorm  = counts + 2048;                     // 8 KB
  float* inv    = enorm + 2048;                      // 8 KB
  float* lossws = inv + 2048;                        // 4 B (+pad)
  u32* offsets  = (u32*)(lossws + 64);               // 8 KB
  u32* cursor   = offsets + 2048;                    // 8 KB
  u32* sorted   = cursor + 2048;                     // 256 KB
  u32* chunkinfo= sorted + 65536;                    // 10 KB
  u32* ntotal   = chunkinfo + MAXCHUNK;              // 4 B
  uint4* list   = (uint4*)(ws + 3145728);            // 1 MB, [65536] uint4

  prep_kernel<<<8704, 256, 0, stream>>>(ze, emb, xh, ehp, enorm, counts, lossws);
  dist_gemm<<<512, 256, 0, stream>>>(xh, ehp, enorm, list);
  finalize_kernel<<<16384, 256, 0, stream>>>(list, ze, emb, wsidx, counts, o_idx);
  scan_kernel<<<1, 256, 0, stream>>>(counts, cs, offsets, cursor, chunkinfo, ntotal,
                                     o_ncs, inv);
  scatter_zero_kernel<<<2304, 256, 0, stream>>>(wsidx, offsets, cursor, sorted,
                                                counts, o_emb);
  zq_seg_kernel<<<MAXCHUNK, 256, 0, stream>>>(ze, emb, ea, inv, offsets, counts, sorted,
                                              chunkinfo, ntotal, o_zq, o_emb, o_nea, lossws);
  tail_kernel<<<2048, 256, 0, stream>>>(counts, ea, inv, o_emb, o_nea, lossws, o_loss);
}